// Round 12
// baseline (589.095 us; speedup 1.0000x reference)
//
#include <hip/hip_runtime.h>
#include <math.h>

#define H 256

typedef float f32x4 __attribute__((ext_vector_type(4)));
typedef _Float16 half8 __attribute__((ext_vector_type(8)));
typedef _Float16 half4 __attribute__((ext_vector_type(4)));
typedef _Float16 half2v __attribute__((ext_vector_type(2)));
typedef unsigned long long u64;

__device__ inline unsigned pkh(float a, float b) {
    auto t = __builtin_amdgcn_cvt_pkrtz(a, b);
    union { decltype(t) h; unsigned u; } v; v.h = t; return v.u;
}
__device__ inline ushort f2h(float f) {
    union { _Float16 h; ushort u; } v; v.h = (_Float16)f; return v.u;
}
// async global->LDS copy, 16B per lane; lds dest must be wave-uniform base
__device__ inline void gload_lds16(const void* gp, void* lp) {
    __builtin_amdgcn_global_load_lds(
        (const __attribute__((address_space(1))) unsigned int*)gp,
        (__attribute__((address_space(3))) unsigned int*)lp,
        16, 0, 0);
}

// ---------------- CSR build ----------------

__global__ void count_deg(const int* __restrict__ dst, int* __restrict__ deg, int E) {
    int e = blockIdx.x * blockDim.x + threadIdx.x;
    if (e < E) atomicAdd(&deg[dst[e]], 1);
}

__global__ void scan_block(const int* __restrict__ deg, int* __restrict__ row,
                           int* __restrict__ btot, int n) {
    __shared__ int wsum[16];
    int tid = threadIdx.x;            // 1024
    int lane = tid & 63, wid = tid >> 6;
    int i = blockIdx.x * 1024 + tid;
    int v = (i < n) ? deg[i] : 0;
    int x = v;
    #pragma unroll
    for (int off = 1; off < 64; off <<= 1) {
        int t = __shfl_up(x, off, 64);
        if (lane >= off) x += t;
    }
    if (lane == 63) wsum[wid] = x;
    __syncthreads();
    int wexc = 0;
    for (int w = 0; w < wid; ++w) wexc += wsum[w];
    int incl = wexc + x;
    if (i < n) row[i + 1] = incl;
    if (tid == 1023) btot[blockIdx.x] = incl;
}

__global__ void scan_tops(const int* __restrict__ btot, int* __restrict__ boff, int nb) {
    __shared__ int wsum[16];
    int tid = threadIdx.x;            // 1024
    int lane = tid & 63, wid = tid >> 6;
    int v = (tid < nb) ? btot[tid] : 0;
    int x = v;
    #pragma unroll
    for (int off = 1; off < 64; off <<= 1) {
        int t = __shfl_up(x, off, 64);
        if (lane >= off) x += t;
    }
    if (lane == 63) wsum[wid] = x;
    __syncthreads();
    int wexc = 0;
    for (int w = 0; w < wid; ++w) wexc += wsum[w];
    if (tid < nb) boff[tid] = wexc + x - v;   // exclusive
}

__global__ void scan_add(const int* __restrict__ boff, int* __restrict__ row, int n) {
    int i = blockIdx.x * 1024 + threadIdx.x;
    if (i == 0) row[0] = 0;
    if (i < n) row[i + 1] += boff[blockIdx.x];
}

__global__ void fill_csr(const int* __restrict__ src, const int* __restrict__ dst,
                         const int* __restrict__ row, int* __restrict__ cursor,
                         int* __restrict__ srcl, int E) {
    int e = blockIdx.x * blockDim.x + threadIdx.x;
    if (e < E) {
        int d = dst[e];
        int p = atomicAdd(&cursor[d], 1);
        srcl[row[d] + p] = src[e];
    }
}

// ---------------- weight prep: fp32 -> fp16 transposed ----------------

__global__ void prep_weights(const float* __restrict__ w10, const float* __restrict__ w20,
                             const float* __restrict__ w11, const float* __restrict__ w21,
                             const float* __restrict__ gw1,
                             ushort* __restrict__ w1t0, ushort* __restrict__ w2t0,
                             ushort* __restrict__ w1t1, ushort* __restrict__ w2t1,
                             ushort* __restrict__ gw1t) {
    int i = blockIdx.x * 256 + threadIdx.x;
    if (i < 32768) {                       // w10: 128x256
        int k = i >> 8, n = i & 255;
        w1t0[n * 128 + k] = f2h(w10[i]);
    } else if (i < 32768 + 65536) {        // w20: 256x256
        int j = i - 32768; int k = j >> 8, n = j & 255;
        w2t0[n * 256 + k] = f2h(w20[j]);
    } else if (i < 32768 + 131072) {       // w11: 256x256
        int j = i - (32768 + 65536); int k = j >> 8, n = j & 255;
        w1t1[n * 256 + k] = f2h(w11[j]);
    } else if (i < 32768 + 196608) {       // w21: 256x256
        int j = i - (32768 + 131072); int k = j >> 8, n = j & 255;
        w2t1[n * 256 + k] = f2h(w21[j]);
    } else if (i < 32768 + 196608 + 32768) { // gw1: 256x128
        int j = i - (32768 + 196608); int k = j >> 7, n = j & 127;
        gw1t[n * 256 + k] = f2h(gw1[j]);
    }
}

// ---------------- x -> fp16 ----------------

__global__ void xcast(const float* __restrict__ x, u64* __restrict__ xb, int n4) {
    int i = blockIdx.x * 256 + threadIdx.x;
    if (i < n4) {
        f32x4 v = ((const f32x4*)x)[i];
        xb[i] = (u64)pkh(v[0], v[1]) | ((u64)pkh(v[2], v[3]) << 32);
    }
}

// ---------------- aggregation (wave per node, 16-deep unroll) ----------------
// Output rows are written with the 16B-granule XOR swizzle (g ^= n&7) so the
// MLP kernel's linear global_load_lds staging lands conflict-free in LDS.

__global__ void aggregate0(const unsigned* __restrict__ xb, const int* __restrict__ row,
                           const int* __restrict__ srcl, unsigned* __restrict__ out, int N) {
    int n = blockIdx.x * 4 + (threadIdx.x >> 6);
    int f = threadIdx.x & 63;
    if (n >= N) return;
    union U { unsigned u; half2v h; };
    int s0 = row[n], s1 = row[n + 1];
    U a[16];
    a[0].u = xb[(size_t)n * 64 + f];
    #pragma unroll
    for (int q = 1; q < 16; ++q) a[q].h = (half2v)0;
    for (int base = s0; base < s1; base += 64) {
        int cnt = s1 - base; if (cnt > 64) cnt = 64;
        int idx = srcl[base + (f < cnt ? f : 0)];
        int j = 0;
        for (; j + 15 < cnt; j += 16) {
            U u[16];
            #pragma unroll
            for (int q = 0; q < 16; ++q)
                u[q].u = xb[(size_t)__builtin_amdgcn_readlane(idx, j + q) * 64 + f];
            #pragma unroll
            for (int q = 0; q < 16; ++q) a[q].h += u[q].h;
        }
        for (; j + 3 < cnt; j += 4) {
            U u[4];
            #pragma unroll
            for (int q = 0; q < 4; ++q)
                u[q].u = xb[(size_t)__builtin_amdgcn_readlane(idx, j + q) * 64 + f];
            #pragma unroll
            for (int q = 0; q < 4; ++q) a[q].h += u[q].h;
        }
        for (; j < cnt; ++j) {
            U u0; u0.u = xb[(size_t)__builtin_amdgcn_readlane(idx, j) * 64 + f];
            a[0].h += u0.h;
        }
    }
    #pragma unroll
    for (int q = 0; q < 8; ++q) a[q].h += a[q + 8].h;
    #pragma unroll
    for (int q = 0; q < 4; ++q) a[q].h += a[q + 4].h;
    a[0].h += a[2].h; a[1].h += a[3].h;
    a[0].h += a[1].h;
    int of = (((f >> 2) ^ (n & 7)) << 2) | (f & 3);   // 16B-granule swizzle
    out[(size_t)n * 64 + of] = a[0].u;
}

__global__ void aggregate1(const u64* __restrict__ h, const int* __restrict__ row,
                           const int* __restrict__ srcl, u64* __restrict__ out, int N) {
    int n = blockIdx.x * 4 + (threadIdx.x >> 6);
    int f = threadIdx.x & 63;
    if (n >= N) return;
    union U { u64 u; half4 h; };
    int s0 = row[n], s1 = row[n + 1];
    U a[16];
    a[0].u = h[(size_t)n * 64 + f];
    #pragma unroll
    for (int q = 1; q < 16; ++q) a[q].h = (half4)0;
    for (int base = s0; base < s1; base += 64) {
        int cnt = s1 - base; if (cnt > 64) cnt = 64;
        int idx = srcl[base + (f < cnt ? f : 0)];
        int j = 0;
        for (; j + 15 < cnt; j += 16) {
            U u[16];
            #pragma unroll
            for (int q = 0; q < 16; ++q)
                u[q].u = h[(size_t)__builtin_amdgcn_readlane(idx, j + q) * 64 + f];
            #pragma unroll
            for (int q = 0; q < 16; ++q) a[q].h += u[q].h;
        }
        for (; j + 3 < cnt; j += 4) {
            U u[4];
            #pragma unroll
            for (int q = 0; q < 4; ++q)
                u[q].u = h[(size_t)__builtin_amdgcn_readlane(idx, j + q) * 64 + f];
            #pragma unroll
            for (int q = 0; q < 4; ++q) a[q].h += u[q].h;
        }
        for (; j < cnt; ++j) {
            U u0; u0.u = h[(size_t)__builtin_amdgcn_readlane(idx, j) * 64 + f];
            a[0].h += u0.h;
        }
    }
    #pragma unroll
    for (int q = 0; q < 8; ++q) a[q].h += a[q + 8].h;
    #pragma unroll
    for (int q = 0; q < 4; ++q) a[q].h += a[q + 4].h;
    a[0].h += a[2].h; a[1].h += a[3].h;
    a[0].h += a[1].h;
    int of = (((f >> 1) ^ (n & 7)) << 1) | (f & 1);   // 16B-granule swizzle
    out[(size_t)n * 64 + of] = a[0].u;
}

// ---------------- fused MFMA MLP + LN (+ gate) ----------------
// 4 waves x 64 nodes/block; ft-split: wave w owns ft-tiles {4w..4w+3}.
// A-tile (pre-swizzled rows) staged async via global_load_lds into LDS once
// per block; GEMM1 reads LDS only. Weights: DEPTH-3 rolling register
// prefetch (wa/wb/wc, compile-time indexed) to cover ~200cy L2 hit latency
// (3x77cy MFMA batches in flight vs 1-ahead's 77cy).
// Swapped MFMA: C col = node (lane&15), C row = feat (4*(lane>>4)+r).

template<int K1, bool DO_GATE>
__global__ void __launch_bounds__(256, 3) mlp_mfma(
        const ushort* __restrict__ hsum, const ushort* __restrict__ w1t,
        const float* __restrict__ b1, const ushort* __restrict__ w2t,
        const float* __restrict__ b2, const float* __restrict__ lng,
        const float* __restrict__ lnb, ushort* __restrict__ hout,
        const ushort* __restrict__ gw1t, const float* __restrict__ gb1,
        const float* __restrict__ gw2, const float* __restrict__ gb2,
        float* __restrict__ gate, int N) {
    constexpr int ROWB = K1 * 2;           // bytes per input row
    constexpr int TILEB = 64 * ROWB;       // staged A-tile bytes
    __shared__ ushort hsum_t[64 * K1];     // swizzled input tile (staged)
    __shared__ ushort hid[64 * 256];       // 32KB, swizzled [node][feat]
    __shared__ float2 lnred[4 * 64];       // [wave][node]
    __shared__ float gred[4 * 64];
    int tid = threadIdx.x;
    int w = tid >> 6, lane = tid & 63;
    int ll = lane & 15, kg = lane >> 4;
    int n0 = blockIdx.x * 64;

    // ---- async stage A-tile: 4KB per round (256 lanes x 16B) ----
    {
        const char* gs = (const char*)hsum;
        #pragma unroll
        for (int r = 0; r < TILEB / 4096; ++r) {
            int off = r * 4096 + w * 1024;        // wave-uniform LDS base
            int myoff = off + lane * 16;
            int mynode = myoff / ROWB;
            int inrow = myoff - mynode * ROWB;
            int gn = n0 + mynode; if (gn >= N) gn = N - 1;
            gload_lds16(gs + (size_t)gn * ROWB + inrow, (char*)hsum_t + off);
        }
    }
    __syncthreads();   // drains vmcnt before barrier

    // ---- GEMM1: B-frags from LDS, weights depth-3 prefetch from L2 ----
    constexpr int KC1 = K1 / 32;
    const ushort* w1base = w1t + (size_t)(16 * 4 * w + ll) * K1;   // + f*16*K1
    f32x4 acc[4][4];
    #pragma unroll
    for (int f = 0; f < 4; ++f)
        #pragma unroll
        for (int nt = 0; nt < 4; ++nt) acc[f][nt] = (f32x4){0.f, 0.f, 0.f, 0.f};
    {
        half8 wa[4], wb[4], wc[4];
        #pragma unroll
        for (int f = 0; f < 4; ++f) {
            wa[f] = *(const half8*)(w1base + (size_t)f * 16 * K1 + kg * 8);
            wb[f] = *(const half8*)(w1base + (size_t)f * 16 * K1 + 32 + kg * 8);
            if (KC1 > 2)
                wc[f] = *(const half8*)(w1base + (size_t)f * 16 * K1 + 64 + kg * 8);
        }
        #pragma unroll
        for (int kc = 0; kc < KC1; ++kc) {
            half8 wn[4];
            if (kc + 3 < KC1) {
                #pragma unroll
                for (int f = 0; f < 4; ++f)
                    wn[f] = *(const half8*)(w1base + (size_t)f * 16 * K1 + (kc + 3) * 32 + kg * 8);
            }
            half8 bfr[4];
            #pragma unroll
            for (int nt = 0; nt < 4; ++nt) {
                int node = 16 * nt + ll;
                bfr[nt] = *(const half8*)((char*)hsum_t + node * ROWB +
                                          (((kc * 4 + kg) ^ (node & 7)) << 4));
            }
            #pragma unroll
            for (int f = 0; f < 4; ++f)
                #pragma unroll
                for (int nt = 0; nt < 4; ++nt)
                    acc[f][nt] = __builtin_amdgcn_mfma_f32_16x16x32_f16(wa[f], bfr[nt], acc[f][nt], 0, 0, 0);
            #pragma unroll
            for (int f = 0; f < 4; ++f) { wa[f] = wb[f]; wb[f] = wc[f]; wc[f] = wn[f]; }
        }
    }
    // bias + relu + pack -> swizzled LDS
    #pragma unroll
    for (int f = 0; f < 4; ++f) {
        int feat0 = 16 * (4 * w + f) + 4 * kg;
        f32x4 bq = *(const f32x4*)(b1 + feat0);
        int fb = feat0 * 2;
        #pragma unroll
        for (int nt = 0; nt < 4; ++nt) {
            int node = 16 * nt + ll;
            float v0 = fmaxf(acc[f][nt][0] + bq[0], 0.f);
            float v1 = fmaxf(acc[f][nt][1] + bq[1], 0.f);
            float v2 = fmaxf(acc[f][nt][2] + bq[2], 0.f);
            float v3 = fmaxf(acc[f][nt][3] + bq[3], 0.f);
            unsigned lo = pkh(v0, v1), hi2 = pkh(v2, v3);
            int sb = node * 512 + ((((fb >> 4) ^ (node & 7))) << 4) + (fb & 15);
            *(u64*)((char*)hid + sb) = (u64)lo | ((u64)hi2 << 32);
        }
    }
    __syncthreads();

    // ---- GEMM2: depth-3 weight prefetch ----
    #pragma unroll
    for (int f = 0; f < 4; ++f)
        #pragma unroll
        for (int nt = 0; nt < 4; ++nt) acc[f][nt] = (f32x4){0.f, 0.f, 0.f, 0.f};
    {
        const ushort* w2base = w2t + (size_t)(16 * 4 * w + ll) * 256;
        half8 wa[4], wb[4], wc[4];
        #pragma unroll
        for (int f = 0; f < 4; ++f) {
            wa[f] = *(const half8*)(w2base + (size_t)f * 16 * 256 + kg * 8);
            wb[f] = *(const half8*)(w2base + (size_t)f * 16 * 256 + 32 + kg * 8);
            wc[f] = *(const half8*)(w2base + (size_t)f * 16 * 256 + 64 + kg * 8);
        }
        #pragma unroll
        for (int kc = 0; kc < 8; ++kc) {
            half8 wn[4];
            if (kc + 3 < 8) {
                #pragma unroll
                for (int f = 0; f < 4; ++f)
                    wn[f] = *(const half8*)(w2base + (size_t)f * 16 * 256 + (kc + 3) * 32 + kg * 8);
            }
            half8 bfr[4];
            int fb = kc * 64 + kg * 16;
            #pragma unroll
            for (int nt = 0; nt < 4; ++nt) {
                int node = 16 * nt + ll;
                int sb = node * 512 + ((((fb >> 4) ^ (node & 7))) << 4);
                bfr[nt] = *(const half8*)((char*)hid + sb);
            }
            #pragma unroll
            for (int f = 0; f < 4; ++f)
                #pragma unroll
                for (int nt = 0; nt < 4; ++nt)
                    acc[f][nt] = __builtin_amdgcn_mfma_f32_16x16x32_f16(wa[f], bfr[nt], acc[f][nt], 0, 0, 0);
            #pragma unroll
            for (int f = 0; f < 4; ++f) { wa[f] = wb[f]; wb[f] = wc[f]; wc[f] = wn[f]; }
        }
    }

    // ---- LayerNorm ----
    float sA[4] = {0, 0, 0, 0}, sB[4] = {0, 0, 0, 0};
    #pragma unroll
    for (int f = 0; f < 4; ++f) {
        int feat0 = 16 * (4 * w + f) + 4 * kg;
        f32x4 bq = *(const f32x4*)(b2 + feat0);
        #pragma unroll
        for (int nt = 0; nt < 4; ++nt) {
            #pragma unroll
            for (int r = 0; r < 4; ++r) {
                float v = acc[f][nt][r] + bq[r];
                acc[f][nt][r] = v;
                sA[nt] += v; sB[nt] += v * v;
            }
        }
    }
    #pragma unroll
    for (int nt = 0; nt < 4; ++nt) {
        sA[nt] += __shfl_xor(sA[nt], 16, 64); sA[nt] += __shfl_xor(sA[nt], 32, 64);
        sB[nt] += __shfl_xor(sB[nt], 16, 64); sB[nt] += __shfl_xor(sB[nt], 32, 64);
    }
    if (lane < 16) {
        #pragma unroll
        for (int nt = 0; nt < 4; ++nt)
            lnred[w * 64 + nt * 16 + ll] = make_float2(sA[nt], sB[nt]);
    }
    __syncthreads();

    float mu[4], rs[4];
    #pragma unroll
    for (int nt = 0; nt < 4; ++nt) {
        float a = 0.f, b = 0.f;
        #pragma unroll
        for (int wv = 0; wv < 4; ++wv) {
            float2 t = lnred[wv * 64 + nt * 16 + ll];
            a += t.x; b += t.y;
        }
        float m = a * (1.f / 256.f);
        mu[nt] = m;
        rs[nt] = rsqrtf(b * (1.f / 256.f) - m * m + 1e-5f);
    }

    // ---- LN apply + relu: write h global (+ hid2 to LDS for gate) ----
    #pragma unroll
    for (int f = 0; f < 4; ++f) {
        int feat0 = 16 * (4 * w + f) + 4 * kg;
        f32x4 gq = *(const f32x4*)(lng + feat0);
        f32x4 bq = *(const f32x4*)(lnb + feat0);
        int fb = feat0 * 2;
        #pragma unroll
        for (int nt = 0; nt < 4; ++nt) {
            int node = 16 * nt + ll;
            int n = n0 + node;
            float v0 = fmaxf((acc[f][nt][0] - mu[nt]) * rs[nt] * gq[0] + bq[0], 0.f);
            float v1 = fmaxf((acc[f][nt][1] - mu[nt]) * rs[nt] * gq[1] + bq[1], 0.f);
            float v2 = fmaxf((acc[f][nt][2] - mu[nt]) * rs[nt] * gq[2] + bq[2], 0.f);
            float v3 = fmaxf((acc[f][nt][3] - mu[nt]) * rs[nt] * gq[3] + bq[3], 0.f);
            unsigned lo = pkh(v0, v1), hi2 = pkh(v2, v3);
            u64 pv = (u64)lo | ((u64)hi2 << 32);
            if (n < N)
                *(u64*)(hout + (size_t)n * 256 + feat0) = pv;
            if (DO_GATE) {
                int sb = node * 512 + ((((fb >> 4) ^ (node & 7))) << 4) + (fb & 15);
                *(u64*)((char*)hid + sb) = pv;
            }
        }
    }

    // ---- gate MLP: depth-3 weight prefetch ----
    if (DO_GATE) {
        __syncthreads();
        f32x4 ga[2][4];
        #pragma unroll
        for (int f = 0; f < 2; ++f)
            #pragma unroll
            for (int nt = 0; nt < 4; ++nt) ga[f][nt] = (f32x4){0.f, 0.f, 0.f, 0.f};
        const ushort* gwbase = gw1t + (size_t)(16 * 2 * w + ll) * 256;
        half8 wa[2], wb[2], wc[2];
        #pragma unroll
        for (int f = 0; f < 2; ++f) {
            wa[f] = *(const half8*)(gwbase + (size_t)f * 16 * 256 + kg * 8);
            wb[f] = *(const half8*)(gwbase + (size_t)f * 16 * 256 + 32 + kg * 8);
            wc[f] = *(const half8*)(gwbase + (size_t)f * 16 * 256 + 64 + kg * 8);
        }
        #pragma unroll
        for (int kc = 0; kc < 8; ++kc) {
            half8 wn[2];
            if (kc + 3 < 8) {
                #pragma unroll
                for (int f = 0; f < 2; ++f)
                    wn[f] = *(const half8*)(gwbase + (size_t)f * 16 * 256 + (kc + 3) * 32 + kg * 8);
            }
            half8 bfr[4];
            int fb = kc * 64 + kg * 16;
            #pragma unroll
            for (int nt = 0; nt < 4; ++nt) {
                int node = 16 * nt + ll;
                int sb = node * 512 + ((((fb >> 4) ^ (node & 7))) << 4);
                bfr[nt] = *(const half8*)((char*)hid + sb);
            }
            #pragma unroll
            for (int f = 0; f < 2; ++f)
                #pragma unroll
                for (int nt = 0; nt < 4; ++nt)
                    ga[f][nt] = __builtin_amdgcn_mfma_f32_16x16x32_f16(wa[f], bfr[nt], ga[f][nt], 0, 0, 0);
            #pragma unroll
            for (int f = 0; f < 2; ++f) { wa[f] = wb[f]; wb[f] = wc[f]; wc[f] = wn[f]; }
        }
        float gp[4] = {0, 0, 0, 0};
        #pragma unroll
        for (int f = 0; f < 2; ++f) {
            int feat0 = 16 * (2 * w + f) + 4 * kg;
            f32x4 gbq = *(const f32x4*)(gb1 + feat0);
            f32x4 gwq = *(const f32x4*)(gw2 + feat0);
            #pragma unroll
            for (int nt = 0; nt < 4; ++nt)
                #pragma unroll
                for (int r = 0; r < 4; ++r)
                    gp[nt] += fmaxf(ga[f][nt][r] + gbq[r], 0.f) * gwq[r];
        }
        #pragma unroll
        for (int nt = 0; nt < 4; ++nt) {
            gp[nt] += __shfl_xor(gp[nt], 16, 64);
            gp[nt] += __shfl_xor(gp[nt], 32, 64);
        }
        if (lane < 16) {
            #pragma unroll
            for (int nt = 0; nt < 4; ++nt)
                gred[w * 64 + nt * 16 + ll] = gp[nt];
        }
        __syncthreads();
        if (w == 0 && lane < 16) {
            #pragma unroll
            for (int nt = 0; nt < 4; ++nt) {
                int n = n0 + 16 * nt + ll;
                if (n < N) {
                    float gs = gred[nt * 16 + ll] + gred[64 + nt * 16 + ll] +
                               gred[128 + nt * 16 + ll] + gred[192 + nt * 16 + ll];
                    gate[n] = gs + gb2[0];
                }
            }
        }
    }
}

// ---------------- graph ranges ----------------

__global__ void boundaries(const int* __restrict__ batch, int* __restrict__ gstart,
                           int* __restrict__ gend, int N) {
    int i = blockIdx.x * blockDim.x + threadIdx.x;
    if (i >= N) return;
    int b = batch[i];
    if (i == 0 || batch[i - 1] != b) gstart[b] = i;
    if (i == N - 1 || batch[i + 1] != b) gend[b] = i + 1;
}

// ---------------- softmax pooling, split ----------------

__global__ void gate_stats(const float* __restrict__ gate, const int* __restrict__ gstart,
                           const int* __restrict__ gend, float* __restrict__ ebuf,
                           float* __restrict__ den) {
    __shared__ float red[256];
    int g = blockIdx.x;
    int tid = threadIdx.x;   // 256
    int s = gstart[g], e = gend[g];
    float lmax = -INFINITY;
    for (int n = s + tid; n < e; n += 256) lmax = fmaxf(lmax, gate[n]);
    red[tid] = lmax;
    __syncthreads();
    for (int off = 128; off > 0; off >>= 1) {
        if (tid < off) red[tid] = fmaxf(red[tid], red[tid + off]);
        __syncthreads();
    }
    float gmax = red[0];
    __syncthreads();
    float lsum = 0.f;
    for (int n = s + tid; n < e; n += 256) {
        float ev = expf(gate[n] - gmax);
        ebuf[n] = ev;
        lsum += ev;
    }
    red[tid] = lsum;
    __syncthreads();
    for (int off = 128; off > 0; off >>= 1) {
        if (tid < off) red[tid] += red[tid + off];
        __syncthreads();
    }
    if (tid == 0) den[g] = red[0];
}

// grid (G, 4), 512 threads: block handles 64 feats of one graph, 16 node groups
__global__ void pool_feat(const ushort* __restrict__ h, const float* __restrict__ ebuf,
                          const float* __restrict__ den, const int* __restrict__ gstart,
                          const int* __restrict__ gend, float* __restrict__ pooled) {
    __shared__ float2 pl[512];
    int g = blockIdx.x, c = blockIdx.y;
    int tid = threadIdx.x;              // 512
    int fq = tid & 31, ng = tid >> 5;   // 32 feat-pairs x 16 node groups
    int s = gstart[g], e = gend[g];
    float2 acc = make_float2(0.f, 0.f);
    for (int n = s + ng; n < e; n += 16) {
        float wv = ebuf[n];
        union { unsigned u; half2v h2; } v;
        v.u = *(const unsigned*)(h + (size_t)n * 256 + c * 64 + fq * 2);
        acc.x += (float)v.h2[0] * wv;
        acc.y += (float)v.h2[1] * wv;
    }
    pl[tid] = acc;
    __syncthreads();
    if (tid < 32) {
        float2 a = pl[tid];
        #pragma unroll
        for (int q = 1; q < 16; ++q) {
            float2 t = pl[q * 32 + tid];
            a.x += t.x; a.y += t.y;
        }
        float d = (e > s) ? den[g] : 1.f;
        float inv = 1.f / d;
        pooled[g * 256 + c * 64 + fq * 2]     = (e > s) ? a.x * inv : 0.f;
        pooled[g * 256 + c * 64 + fq * 2 + 1] = (e > s) ? a.y * inv : 0.f;
    }
}

__global__ void cls_kernel(const float* __restrict__ pooled,
                           const float* __restrict__ cw1, const float* __restrict__ cb1,
                           const float* __restrict__ cw2, const float* __restrict__ cb2,
                           float* __restrict__ out) {
    __shared__ float pl[256];
    __shared__ float c2[256];
    int g = blockIdx.x;
    int tid = threadIdx.x;   // 128
    pl[tid] = pooled[g * 256 + tid];
    pl[tid + 128] = pooled[g * 256 + 128 + tid];
    __syncthreads();
    float a = cb1[tid];
    #pragma unroll 2
    for (int k = 0; k < H; ++k) a = fmaf(pl[k], cw1[(size_t)k * 128 + tid], a);
    a = fmaxf(a, 0.f);
    c2[tid * 2 + 0] = a * cw2[tid * 2 + 0];
    c2[tid * 2 + 1] = a * cw2[tid * 2 + 1];
    __syncthreads();
    if (tid < 2) {
        float sres = cb2[tid];
        for (int p = 0; p < 128; ++p) sres += c2[p * 2 + tid];
        out[g * 2 + tid] = sres;
    }
}

// ---------------- launch ----------------

extern "C" void kernel_launch(void* const* d_in, const int* in_sizes, int n_in,
                              void* d_out, int out_size, void* d_ws, size_t ws_size,
                              hipStream_t stream) {
    const float* x     = (const float*)d_in[0];
    const int*   ei    = (const int*)d_in[1];
    const int*   batch = (const int*)d_in[2];
    const float* w1_0  = (const float*)d_in[4];
    const float* b1_0  = (const float*)d_in[5];
    const float* w2_0  = (const float*)d_in[6];
    const float* b2_0  = (const float*)d_in[7];
    const float* lng0  = (const float*)d_in[8];
    const float* lnb0  = (const float*)d_in[9];
    const float* w1_1  = (const float*)d_in[10];
    const float* b1_1  = (const float*)d_in[11];
    const float* w2_1  = (const float*)d_in[12];
    const float* b2_1  = (const float*)d_in[13];
    const float* lng1  = (const float*)d_in[14];
    const float* lnb1  = (const float*)d_in[15];
    const float* gw1   = (const float*)d_in[16];
    const float* gb1   = (const float*)d_in[17];
    const float* gw2   = (const float*)d_in[18];
    const float* gb2   = (const float*)d_in[19];
    const float* cw1   = (const float*)d_in[20];
    const float* cb1   = (const float*)d_in[21];
    const float* cw2   = (const float*)d_in[22];
    const float* cb2   = (const float*)d_in[23];

    int N = in_sizes[2];
    int E = in_sizes[1] / 2;
    int G = out_size / 2;
    const int* src = ei;
    const int* dst = ei + E;

    char* p = (char*)d_ws;
    auto alloc = [&](size_t bytes) {
        char* r = p;
        p += (bytes + 255) & ~(size_t)255;
        return r;
    };
    int*    row    = (int*)alloc((size_t)(N + 1) * 4);
    int*    cursor = (int*)alloc((size_t)N * 4);
    int*    srcl   = (int*)alloc((size_t)E * 4);
    float*  gate   = (float*)alloc((size_t)N * 4);
    float*  ebuf   = (float*)alloc((size_t)N * 4);
    float*  den    = (float*)alloc((size_t)G * 4);
    float*  pooled = (float*)alloc((size_t)G * 256 * 4);
    int*    gstart = (int*)alloc((size_t)G * 4);
    int*    gend   = (int*)alloc((size_t)G * 4);
    int*    btot   = (int*)alloc(1024 * 4);
    int*    boff   = (int*)alloc(1024 * 4);
    ushort* xb     = (ushort*)alloc((size_t)N * 128 * 2);
    ushort* hsum0  = (ushort*)alloc((size_t)N * 128 * 2);
    ushort* h1     = (ushort*)alloc((size_t)N * 256 * 2);
    ushort* hsum1  = (ushort*)alloc((size_t)N * 256 * 2);
    ushort* h2     = (ushort*)alloc((size_t)N * 256 * 2);
    ushort* w1t0   = (ushort*)alloc(128 * 256 * 2);
    ushort* w2t0   = (ushort*)alloc(256 * 256 * 2);
    ushort* w1t1   = (ushort*)alloc(256 * 256 * 2);
    ushort* w2t1   = (ushort*)alloc(256 * 256 * 2);
    ushort* gw1t   = (ushort*)alloc(128 * 256 * 2);

    // weight prep, x cast, CSR build
    prep_weights<<<1024, 256, 0, stream>>>(w1_0, w2_0, w1_1, w2_1, gw1,
                                           w1t0, w2t0, w1t1, w2t1, gw1t);
    xcast<<<(N * 32 + 255) / 256, 256, 0, stream>>>(x, (u64*)xb, N * 32);
    hipMemsetAsync(cursor, 0, (size_t)N * 4, stream);
    count_deg<<<(E + 255) / 256, 256, 0, stream>>>(dst, cursor, E);
    int nb = (N + 1023) / 1024;
    scan_block<<<nb, 1024, 0, stream>>>(cursor, row, btot, N);
    scan_tops<<<1, 1024, 0, stream>>>(btot, boff, nb);
    scan_add<<<nb, 1024, 0, stream>>>(boff, row, N);
    hipMemsetAsync(cursor, 0, (size_t)N * 4, stream);
    fill_csr<<<(E + 255) / 256, 256, 0, stream>>>(src, dst, row, cursor, srcl, E);

    int agg_blocks = (N + 3) / 4;
    int mlp_blocks = (N + 63) / 64;
    // layer 0
    aggregate0<<<agg_blocks, 256, 0, stream>>>((const unsigned*)xb, row, srcl,
                                               (unsigned*)hsum0, N);
    mlp_mfma<128, false><<<mlp_blocks, 256, 0, stream>>>(
        hsum0, w1t0, b1_0, w2t0, b2_0, lng0, lnb0, h1,
        nullptr, nullptr, nullptr, nullptr, nullptr, N);
    // layer 1 + fused gate
    aggregate1<<<agg_blocks, 256, 0, stream>>>((const u64*)h1, row, srcl,
                                               (u64*)hsum1, N);
    mlp_mfma<256, true><<<mlp_blocks, 256, 0, stream>>>(
        hsum1, w1t1, b1_1, w2t1, b2_1, lng1, lnb1, h2,
        gw1t, gb1, gw2, gb2, gate, N);
    // pooling + classifier
    hipMemsetAsync(gstart, 0, (size_t)G * 4, stream);
    hipMemsetAsync(gend, 0, (size_t)G * 4, stream);
    boundaries<<<(N + 255) / 256, 256, 0, stream>>>(batch, gstart, gend, N);
    gate_stats<<<G, 256, 0, stream>>>(gate, gstart, gend, ebuf, den);
    pool_feat<<<dim3(G, 4), 512, 0, stream>>>(h2, ebuf, den, gstart, gend, pooled);
    cls_kernel<<<G, 128, 0, stream>>>(pooled, cw1, cb1, cw2, cb2, (float*)d_out);
}

// Round 13
// 503.025 us; speedup vs baseline: 1.1711x; 1.1711x over previous
//
#include <hip/hip_runtime.h>
#include <math.h>

#define H 256

typedef float f32x4 __attribute__((ext_vector_type(4)));
typedef _Float16 half8 __attribute__((ext_vector_type(8)));
typedef _Float16 half4 __attribute__((ext_vector_type(4)));
typedef _Float16 half2v __attribute__((ext_vector_type(2)));
typedef unsigned long long u64;

__device__ inline unsigned pkh(float a, float b) {
    auto t = __builtin_amdgcn_cvt_pkrtz(a, b);
    union { decltype(t) h; unsigned u; } v; v.h = t; return v.u;
}
__device__ inline ushort f2h(float f) {
    union { _Float16 h; ushort u; } v; v.h = (_Float16)f; return v.u;
}
// async global->LDS copy, 16B per lane; lds dest must be wave-uniform base
__device__ inline void gload_lds16(const void* gp, void* lp) {
    __builtin_amdgcn_global_load_lds(
        (const __attribute__((address_space(1))) unsigned int*)gp,
        (__attribute__((address_space(3))) unsigned int*)lp,
        16, 0, 0);
}

// ---------------- bucketed CSR build ----------------
// bucket b = dst >> SHIFT (512 nodes/bucket, NB <= 256 buckets)

__global__ void bucket_hist(const int* __restrict__ dst, int* __restrict__ bktCnt,
                            int E, int shift) {
    __shared__ int h[256];
    int tid = threadIdx.x;
    h[tid] = 0;
    __syncthreads();
    for (int e = blockIdx.x * 256 + tid; e < E; e += gridDim.x * 256)
        atomicAdd(&h[dst[e] >> shift], 1);
    __syncthreads();
    if (h[tid]) atomicAdd(&bktCnt[tid], h[tid]);
}

// 1 block, 256 threads; nb <= 256
__global__ void scan_buckets(const int* __restrict__ cnt, int* __restrict__ base,
                             int* __restrict__ cur, int nb) {
    __shared__ int ws[4];
    int tid = threadIdx.x, lane = tid & 63, wid = tid >> 6;
    int v = (tid < nb) ? cnt[tid] : 0;
    int x = v;
    #pragma unroll
    for (int off = 1; off < 64; off <<= 1) {
        int t = __shfl_up(x, off, 64);
        if (lane >= off) x += t;
    }
    if (lane == 63) ws[wid] = x;
    __syncthreads();
    int wexc = 0;
    for (int w = 0; w < wid; ++w) wexc += ws[w];
    int excl = wexc + x - v;
    if (tid < nb) { base[tid] = excl; cur[tid] = excl; }
    if (tid == nb - 1) base[nb] = excl + v;   // = E
}

// bin edges into bucket-grouped pair buffer; 4096 edges/block
#define BIN_EPT 16
__global__ void __launch_bounds__(256) bin_pass(
        const int* __restrict__ src, const int* __restrict__ dst,
        int* __restrict__ bktCur, u64* __restrict__ pairs, int E, int shift) {
    __shared__ int hist[256];
    __shared__ int base_s[256];
    int tid = threadIdx.x;
    hist[tid] = 0;
    __syncthreads();
    int e0 = blockIdx.x * (256 * BIN_EPT);
    int mys[BIN_EPT], myd[BIN_EPT], myslot[BIN_EPT];
    #pragma unroll
    for (int i = 0; i < BIN_EPT; ++i) {
        int e = e0 + i * 256 + tid;
        if (e < E) {
            mys[i] = src[e];
            myd[i] = dst[e];
            myslot[i] = atomicAdd(&hist[myd[i] >> shift], 1);
        }
    }
    __syncthreads();
    base_s[tid] = hist[tid] ? atomicAdd(&bktCur[tid], hist[tid]) : 0;
    __syncthreads();
    #pragma unroll
    for (int i = 0; i < BIN_EPT; ++i) {
        int e = e0 + i * 256 + tid;
        if (e < E)
            pairs[base_s[myd[i] >> shift] + myslot[i]] =
                ((u64)(unsigned)myd[i] << 32) | (unsigned)mys[i];
    }
}

// one block per bucket: LDS degree count -> scan -> row + srcl fill
__global__ void __launch_bounds__(256) fill_bucket(
        const u64* __restrict__ pairs, const int* __restrict__ bktBase,
        int* __restrict__ row, int* __restrict__ srcl, int N, int shift, int NB) {
    __shared__ int deg[512];
    __shared__ int ws[4];
    int b = blockIdx.x;
    int n0 = b << shift;
    int nodes = (1 << shift); if (n0 + nodes > N) nodes = N - n0;
    int e0 = bktBase[b], e1 = bktBase[b + 1];
    int tid = threadIdx.x, lane = tid & 63, wid = tid >> 6;
    deg[tid] = 0; deg[tid + 256] = 0;
    __syncthreads();
    for (int e = e0 + tid; e < e1; e += 256) {
        int d = (int)(pairs[e] >> 32) - n0;
        atomicAdd(&deg[d], 1);
    }
    __syncthreads();
    // exclusive scan of 512 (2 elems/thread)
    int a0 = deg[2 * tid], a1 = deg[2 * tid + 1];
    int ps = a0 + a1;
    int x = ps;
    #pragma unroll
    for (int off = 1; off < 64; off <<= 1) {
        int t = __shfl_up(x, off, 64);
        if (lane >= off) x += t;
    }
    if (lane == 63) ws[wid] = x;
    __syncthreads();
    int wexc = 0;
    for (int w = 0; w < wid; ++w) wexc += ws[w];
    int p0 = wexc + x - ps;      // exclusive prefix of elem 2t
    int p1 = p0 + a0;
    if (2 * tid < nodes)     row[n0 + 2 * tid]     = e0 + p0;
    if (2 * tid + 1 < nodes) row[n0 + 2 * tid + 1] = e0 + p1;
    if (b == NB - 1 && tid == 0) row[N] = e1;
    __syncthreads();
    deg[2 * tid] = e0 + p0;
    deg[2 * tid + 1] = e0 + p1;
    __syncthreads();
    for (int e = e0 + tid; e < e1; e += 256) {
        u64 pr = pairs[e];
        int d = (int)(pr >> 32) - n0;
        int p = atomicAdd(&deg[d], 1);
        srcl[p] = (int)(pr & 0xffffffffu);
    }
}

// ---------------- weight prep: fp32 -> fp16 transposed ----------------

__global__ void prep_weights(const float* __restrict__ w10, const float* __restrict__ w20,
                             const float* __restrict__ w11, const float* __restrict__ w21,
                             const float* __restrict__ gw1,
                             ushort* __restrict__ w1t0, ushort* __restrict__ w2t0,
                             ushort* __restrict__ w1t1, ushort* __restrict__ w2t1,
                             ushort* __restrict__ gw1t) {
    int i = blockIdx.x * 256 + threadIdx.x;
    if (i < 32768) {                       // w10: 128x256
        int k = i >> 8, n = i & 255;
        w1t0[n * 128 + k] = f2h(w10[i]);
    } else if (i < 32768 + 65536) {        // w20: 256x256
        int j = i - 32768; int k = j >> 8, n = j & 255;
        w2t0[n * 256 + k] = f2h(w20[j]);
    } else if (i < 32768 + 131072) {       // w11: 256x256
        int j = i - (32768 + 65536); int k = j >> 8, n = j & 255;
        w1t1[n * 256 + k] = f2h(w11[j]);
    } else if (i < 32768 + 196608) {       // w21: 256x256
        int j = i - (32768 + 131072); int k = j >> 8, n = j & 255;
        w2t1[n * 256 + k] = f2h(w21[j]);
    } else if (i < 32768 + 196608 + 32768) { // gw1: 256x128
        int j = i - (32768 + 196608); int k = j >> 7, n = j & 127;
        gw1t[n * 256 + k] = f2h(gw1[j]);
    }
}

// ---------------- x -> fp16 ----------------

__global__ void xcast(const float* __restrict__ x, u64* __restrict__ xb, int n4) {
    int i = blockIdx.x * 256 + threadIdx.x;
    if (i < n4) {
        f32x4 v = ((const f32x4*)x)[i];
        xb[i] = (u64)pkh(v[0], v[1]) | ((u64)pkh(v[2], v[3]) << 32);
    }
}

// ---------------- aggregation (wave per node, 16-deep unroll) ----------------
// Output rows are written with the 16B-granule XOR swizzle (g ^= n&7) so the
// MLP kernel's linear global_load_lds staging lands conflict-free in LDS.

__global__ void aggregate0(const unsigned* __restrict__ xb, const int* __restrict__ row,
                           const int* __restrict__ srcl, unsigned* __restrict__ out, int N) {
    int n = blockIdx.x * 4 + (threadIdx.x >> 6);
    int f = threadIdx.x & 63;
    if (n >= N) return;
    union U { unsigned u; half2v h; };
    int s0 = row[n], s1 = row[n + 1];
    U a[16];
    a[0].u = xb[(size_t)n * 64 + f];
    #pragma unroll
    for (int q = 1; q < 16; ++q) a[q].h = (half2v)0;
    for (int base = s0; base < s1; base += 64) {
        int cnt = s1 - base; if (cnt > 64) cnt = 64;
        int idx = srcl[base + (f < cnt ? f : 0)];
        int j = 0;
        for (; j + 15 < cnt; j += 16) {
            U u[16];
            #pragma unroll
            for (int q = 0; q < 16; ++q)
                u[q].u = xb[(size_t)__builtin_amdgcn_readlane(idx, j + q) * 64 + f];
            #pragma unroll
            for (int q = 0; q < 16; ++q) a[q].h += u[q].h;
        }
        for (; j + 3 < cnt; j += 4) {
            U u[4];
            #pragma unroll
            for (int q = 0; q < 4; ++q)
                u[q].u = xb[(size_t)__builtin_amdgcn_readlane(idx, j + q) * 64 + f];
            #pragma unroll
            for (int q = 0; q < 4; ++q) a[q].h += u[q].h;
        }
        for (; j < cnt; ++j) {
            U u0; u0.u = xb[(size_t)__builtin_amdgcn_readlane(idx, j) * 64 + f];
            a[0].h += u0.h;
        }
    }
    #pragma unroll
    for (int q = 0; q < 8; ++q) a[q].h += a[q + 8].h;
    #pragma unroll
    for (int q = 0; q < 4; ++q) a[q].h += a[q + 4].h;
    a[0].h += a[2].h; a[1].h += a[3].h;
    a[0].h += a[1].h;
    int of = (((f >> 2) ^ (n & 7)) << 2) | (f & 3);   // 16B-granule swizzle
    out[(size_t)n * 64 + of] = a[0].u;
}

__global__ void aggregate1(const u64* __restrict__ h, const int* __restrict__ row,
                           const int* __restrict__ srcl, u64* __restrict__ out, int N) {
    int n = blockIdx.x * 4 + (threadIdx.x >> 6);
    int f = threadIdx.x & 63;
    if (n >= N) return;
    union U { u64 u; half4 h; };
    int s0 = row[n], s1 = row[n + 1];
    U a[16];
    a[0].u = h[(size_t)n * 64 + f];
    #pragma unroll
    for (int q = 1; q < 16; ++q) a[q].h = (half4)0;
    for (int base = s0; base < s1; base += 64) {
        int cnt = s1 - base; if (cnt > 64) cnt = 64;
        int idx = srcl[base + (f < cnt ? f : 0)];
        int j = 0;
        for (; j + 15 < cnt; j += 16) {
            U u[16];
            #pragma unroll
            for (int q = 0; q < 16; ++q)
                u[q].u = h[(size_t)__builtin_amdgcn_readlane(idx, j + q) * 64 + f];
            #pragma unroll
            for (int q = 0; q < 16; ++q) a[q].h += u[q].h;
        }
        for (; j + 3 < cnt; j += 4) {
            U u[4];
            #pragma unroll
            for (int q = 0; q < 4; ++q)
                u[q].u = h[(size_t)__builtin_amdgcn_readlane(idx, j + q) * 64 + f];
            #pragma unroll
            for (int q = 0; q < 4; ++q) a[q].h += u[q].h;
        }
        for (; j < cnt; ++j) {
            U u0; u0.u = h[(size_t)__builtin_amdgcn_readlane(idx, j) * 64 + f];
            a[0].h += u0.h;
        }
    }
    #pragma unroll
    for (int q = 0; q < 8; ++q) a[q].h += a[q + 8].h;
    #pragma unroll
    for (int q = 0; q < 4; ++q) a[q].h += a[q + 4].h;
    a[0].h += a[2].h; a[1].h += a[3].h;
    a[0].h += a[1].h;
    int of = (((f >> 1) ^ (n & 7)) << 1) | (f & 1);   // 16B-granule swizzle
    out[(size_t)n * 64 + of] = a[0].u;
}

// ---------------- fused MFMA MLP + LN (+ gate) ----------------
// 4 waves x 64 nodes/block; ft-split: wave w owns ft-tiles {4w..4w+3}.
// A-tile (pre-swizzled rows) staged async via global_load_lds into LDS once
// per block; GEMM1 reads LDS only (+ L2-hot weights, 1-ahead prefetch).
// Swapped MFMA: C col = node (lane&15), C row = feat (4*(lane>>4)+r).

template<int K1, bool DO_GATE>
__global__ void __launch_bounds__(256, 3) mlp_mfma(
        const ushort* __restrict__ hsum, const ushort* __restrict__ w1t,
        const float* __restrict__ b1, const ushort* __restrict__ w2t,
        const float* __restrict__ b2, const float* __restrict__ lng,
        const float* __restrict__ lnb, ushort* __restrict__ hout,
        const ushort* __restrict__ gw1t, const float* __restrict__ gb1,
        const float* __restrict__ gw2, const float* __restrict__ gb2,
        float* __restrict__ gate, int N) {
    constexpr int ROWB = K1 * 2;           // bytes per input row
    constexpr int TILEB = 64 * ROWB;       // staged A-tile bytes
    __shared__ ushort hsum_t[64 * K1];     // swizzled input tile (staged)
    __shared__ ushort hid[64 * 256];       // 32KB, swizzled [node][feat]
    __shared__ float2 lnred[4 * 64];       // [wave][node]
    __shared__ float gred[4 * 64];
    int tid = threadIdx.x;
    int w = tid >> 6, lane = tid & 63;
    int ll = lane & 15, kg = lane >> 4;
    int n0 = blockIdx.x * 64;

    // ---- async stage A-tile: 4KB per round (256 lanes x 16B) ----
    {
        const char* gs = (const char*)hsum;
        #pragma unroll
        for (int r = 0; r < TILEB / 4096; ++r) {
            int off = r * 4096 + w * 1024;        // wave-uniform LDS base
            int myoff = off + lane * 16;
            int mynode = myoff / ROWB;
            int inrow = myoff - mynode * ROWB;
            int gn = n0 + mynode; if (gn >= N) gn = N - 1;
            gload_lds16(gs + (size_t)gn * ROWB + inrow, (char*)hsum_t + off);
        }
    }
    __syncthreads();   // drains vmcnt before barrier

    // ---- GEMM1: B-frags from LDS, weights 1-ahead from L2 ----
    constexpr int KC1 = K1 / 32;
    f32x4 acc[4][4];
    #pragma unroll
    for (int f = 0; f < 4; ++f)
        #pragma unroll
        for (int nt = 0; nt < 4; ++nt) acc[f][nt] = (f32x4){0.f, 0.f, 0.f, 0.f};
    {
        half8 wcur[4];
        #pragma unroll
        for (int f = 0; f < 4; ++f)
            wcur[f] = *(const half8*)(w1t + (size_t)(16 * (4 * w + f) + ll) * K1 + kg * 8);
        #pragma unroll
        for (int kc = 0; kc < KC1; ++kc) {
            half8 wnx[4];
            if (kc + 1 < KC1) {
                #pragma unroll
                for (int f = 0; f < 4; ++f)
                    wnx[f] = *(const half8*)(w1t + (size_t)(16 * (4 * w + f) + ll) * K1 + (kc + 1) * 32 + kg * 8);
            }
            half8 bfr[4];
            #pragma unroll
            for (int nt = 0; nt < 4; ++nt) {
                int node = 16 * nt + ll;
                bfr[nt] = *(const half8*)((char*)hsum_t + node * ROWB +
                                          (((kc * 4 + kg) ^ (node & 7)) << 4));
            }
            #pragma unroll
            for (int f = 0; f < 4; ++f)
                #pragma unroll
                for (int nt = 0; nt < 4; ++nt)
                    acc[f][nt] = __builtin_amdgcn_mfma_f32_16x16x32_f16(wcur[f], bfr[nt], acc[f][nt], 0, 0, 0);
            if (kc + 1 < KC1) {
                #pragma unroll
                for (int f = 0; f < 4; ++f) wcur[f] = wnx[f];
            }
        }
    }
    // bias + relu + pack -> swizzled LDS
    #pragma unroll
    for (int f = 0; f < 4; ++f) {
        int feat0 = 16 * (4 * w + f) + 4 * kg;
        f32x4 bq = *(const f32x4*)(b1 + feat0);
        int fb = feat0 * 2;
        #pragma unroll
        for (int nt = 0; nt < 4; ++nt) {
            int node = 16 * nt + ll;
            float v0 = fmaxf(acc[f][nt][0] + bq[0], 0.f);
            float v1 = fmaxf(acc[f][nt][1] + bq[1], 0.f);
            float v2 = fmaxf(acc[f][nt][2] + bq[2], 0.f);
            float v3 = fmaxf(acc[f][nt][3] + bq[3], 0.f);
            unsigned lo = pkh(v0, v1), hi2 = pkh(v2, v3);
            int sb = node * 512 + ((((fb >> 4) ^ (node & 7))) << 4) + (fb & 15);
            *(u64*)((char*)hid + sb) = (u64)lo | ((u64)hi2 << 32);
        }
    }
    __syncthreads();

    // ---- GEMM2 with 1-ahead weight prefetch (LDS reads stay inline) ----
    #pragma unroll
    for (int f = 0; f < 4; ++f)
        #pragma unroll
        for (int nt = 0; nt < 4; ++nt) acc[f][nt] = (f32x4){0.f, 0.f, 0.f, 0.f};
    {
        half8 wcur[4];
        #pragma unroll
        for (int f = 0; f < 4; ++f)
            wcur[f] = *(const half8*)(w2t + (size_t)(16 * (4 * w + f) + ll) * 256 + kg * 8);
        #pragma unroll
        for (int kc = 0; kc < 8; ++kc) {
            half8 wnx[4];
            if (kc < 7) {
                #pragma unroll
                for (int f = 0; f < 4; ++f)
                    wnx[f] = *(const half8*)(w2t + (size_t)(16 * (4 * w + f) + ll) * 256 + (kc + 1) * 32 + kg * 8);
            }
            half8 bfr[4];
            int fb = kc * 64 + kg * 16;
            #pragma unroll
            for (int nt = 0; nt < 4; ++nt) {
                int node = 16 * nt + ll;
                int sb = node * 512 + ((((fb >> 4) ^ (node & 7))) << 4);
                bfr[nt] = *(const half8*)((char*)hid + sb);
            }
            #pragma unroll
            for (int f = 0; f < 4; ++f)
                #pragma unroll
                for (int nt = 0; nt < 4; ++nt)
                    acc[f][nt] = __builtin_amdgcn_mfma_f32_16x16x32_f16(wcur[f], bfr[nt], acc[f][nt], 0, 0, 0);
            if (kc < 7) {
                #pragma unroll
                for (int f = 0; f < 4; ++f) wcur[f] = wnx[f];
            }
        }
    }

    // ---- LayerNorm ----
    float sA[4] = {0, 0, 0, 0}, sB[4] = {0, 0, 0, 0};
    #pragma unroll
    for (int f = 0; f < 4; ++f) {
        int feat0 = 16 * (4 * w + f) + 4 * kg;
        f32x4 bq = *(const f32x4*)(b2 + feat0);
        #pragma unroll
        for (int nt = 0; nt < 4; ++nt) {
            #pragma unroll
            for (int r = 0; r < 4; ++r) {
                float v = acc[f][nt][r] + bq[r];
                acc[f][nt][r] = v;
                sA[nt] += v; sB[nt] += v * v;
            }
        }
    }
    #pragma unroll
    for (int nt = 0; nt < 4; ++nt) {
        sA[nt] += __shfl_xor(sA[nt], 16, 64); sA[nt] += __shfl_xor(sA[nt], 32, 64);
        sB[nt] += __shfl_xor(sB[nt], 16, 64); sB[nt] += __shfl_xor(sB[nt], 32, 64);
    }
    if (lane < 16) {
        #pragma unroll
        for (int nt = 0; nt < 4; ++nt)
            lnred[w * 64 + nt * 16 + ll] = make_float2(sA[nt], sB[nt]);
    }
    __syncthreads();

    float mu[4], rs[4];
    #pragma unroll
    for (int nt = 0; nt < 4; ++nt) {
        float a = 0.f, b = 0.f;
        #pragma unroll
        for (int wv = 0; wv < 4; ++wv) {
            float2 t = lnred[wv * 64 + nt * 16 + ll];
            a += t.x; b += t.y;
        }
        float m = a * (1.f / 256.f);
        mu[nt] = m;
        rs[nt] = rsqrtf(b * (1.f / 256.f) - m * m + 1e-5f);
    }

    // ---- LN apply + relu: write h global (+ hid2 to LDS for gate) ----
    #pragma unroll
    for (int f = 0; f < 4; ++f) {
        int feat0 = 16 * (4 * w + f) + 4 * kg;
        f32x4 gq = *(const f32x4*)(lng + feat0);
        f32x4 bq = *(const f32x4*)(lnb + feat0);
        int fb = feat0 * 2;
        #pragma unroll
        for (int nt = 0; nt < 4; ++nt) {
            int node = 16 * nt + ll;
            int n = n0 + node;
            float v0 = fmaxf((acc[f][nt][0] - mu[nt]) * rs[nt] * gq[0] + bq[0], 0.f);
            float v1 = fmaxf((acc[f][nt][1] - mu[nt]) * rs[nt] * gq[1] + bq[1], 0.f);
            float v2 = fmaxf((acc[f][nt][2] - mu[nt]) * rs[nt] * gq[2] + bq[2], 0.f);
            float v3 = fmaxf((acc[f][nt][3] - mu[nt]) * rs[nt] * gq[3] + bq[3], 0.f);
            unsigned lo = pkh(v0, v1), hi2 = pkh(v2, v3);
            u64 pv = (u64)lo | ((u64)hi2 << 32);
            if (n < N)
                *(u64*)(hout + (size_t)n * 256 + feat0) = pv;
            if (DO_GATE) {
                int sb = node * 512 + ((((fb >> 4) ^ (node & 7))) << 4) + (fb & 15);
                *(u64*)((char*)hid + sb) = pv;
            }
        }
    }

    // ---- gate MLP with 1-ahead weight prefetch ----
    if (DO_GATE) {
        __syncthreads();
        f32x4 ga[2][4];
        #pragma unroll
        for (int f = 0; f < 2; ++f)
            #pragma unroll
            for (int nt = 0; nt < 4; ++nt) ga[f][nt] = (f32x4){0.f, 0.f, 0.f, 0.f};
        half8 wcur[2];
        #pragma unroll
        for (int f = 0; f < 2; ++f)
            wcur[f] = *(const half8*)(gw1t + (size_t)(16 * (2 * w + f) + ll) * 256 + kg * 8);
        #pragma unroll
        for (int kc = 0; kc < 8; ++kc) {
            half8 wnx[2];
            if (kc < 7) {
                #pragma unroll
                for (int f = 0; f < 2; ++f)
                    wnx[f] = *(const half8*)(gw1t + (size_t)(16 * (2 * w + f) + ll) * 256 + (kc + 1) * 32 + kg * 8);
            }
            half8 bfr[4];
            int fb = kc * 64 + kg * 16;
            #pragma unroll
            for (int nt = 0; nt < 4; ++nt) {
                int node = 16 * nt + ll;
                int sb = node * 512 + ((((fb >> 4) ^ (node & 7))) << 4);
                bfr[nt] = *(const half8*)((char*)hid + sb);
            }
            #pragma unroll
            for (int f = 0; f < 2; ++f)
                #pragma unroll
                for (int nt = 0; nt < 4; ++nt)
                    ga[f][nt] = __builtin_amdgcn_mfma_f32_16x16x32_f16(wcur[f], bfr[nt], ga[f][nt], 0, 0, 0);
            if (kc < 7) {
                #pragma unroll
                for (int f = 0; f < 2; ++f) wcur[f] = wnx[f];
            }
        }
        float gp[4] = {0, 0, 0, 0};
        #pragma unroll
        for (int f = 0; f < 2; ++f) {
            int feat0 = 16 * (2 * w + f) + 4 * kg;
            f32x4 gbq = *(const f32x4*)(gb1 + feat0);
            f32x4 gwq = *(const f32x4*)(gw2 + feat0);
            #pragma unroll
            for (int nt = 0; nt < 4; ++nt)
                #pragma unroll
                for (int r = 0; r < 4; ++r)
                    gp[nt] += fmaxf(ga[f][nt][r] + gbq[r], 0.f) * gwq[r];
        }
        #pragma unroll
        for (int nt = 0; nt < 4; ++nt) {
            gp[nt] += __shfl_xor(gp[nt], 16, 64);
            gp[nt] += __shfl_xor(gp[nt], 32, 64);
        }
        if (lane < 16) {
            #pragma unroll
            for (int nt = 0; nt < 4; ++nt)
                gred[w * 64 + nt * 16 + ll] = gp[nt];
        }
        __syncthreads();
        if (w == 0 && lane < 16) {
            #pragma unroll
            for (int nt = 0; nt < 4; ++nt) {
                int n = n0 + 16 * nt + ll;
                if (n < N) {
                    float gs = gred[nt * 16 + ll] + gred[64 + nt * 16 + ll] +
                               gred[128 + nt * 16 + ll] + gred[192 + nt * 16 + ll];
                    gate[n] = gs + gb2[0];
                }
            }
        }
    }
}

// ---------------- graph ranges ----------------

__global__ void boundaries(const int* __restrict__ batch, int* __restrict__ gstart,
                           int* __restrict__ gend, int N) {
    int i = blockIdx.x * blockDim.x + threadIdx.x;
    if (i >= N) return;
    int b = batch[i];
    if (i == 0 || batch[i - 1] != b) gstart[b] = i;
    if (i == N - 1 || batch[i + 1] != b) gend[b] = i + 1;
}

// ---------------- softmax pooling, split ----------------

__global__ void gate_stats(const float* __restrict__ gate, const int* __restrict__ gstart,
                           const int* __restrict__ gend, float* __restrict__ ebuf,
                           float* __restrict__ den) {
    __shared__ float red[256];
    int g = blockIdx.x;
    int tid = threadIdx.x;   // 256
    int s = gstart[g], e = gend[g];
    float lmax = -INFINITY;
    for (int n = s + tid; n < e; n += 256) lmax = fmaxf(lmax, gate[n]);
    red[tid] = lmax;
    __syncthreads();
    for (int off = 128; off > 0; off >>= 1) {
        if (tid < off) red[tid] = fmaxf(red[tid], red[tid + off]);
        __syncthreads();
    }
    float gmax = red[0];
    __syncthreads();
    float lsum = 0.f;
    for (int n = s + tid; n < e; n += 256) {
        float ev = expf(gate[n] - gmax);
        ebuf[n] = ev;
        lsum += ev;
    }
    red[tid] = lsum;
    __syncthreads();
    for (int off = 128; off > 0; off >>= 1) {
        if (tid < off) red[tid] += red[tid + off];
        __syncthreads();
    }
    if (tid == 0) den[g] = red[0];
}

// grid (G, 4), 512 threads: block handles 64 feats of one graph, 16 node groups
__global__ void pool_feat(const ushort* __restrict__ h, const float* __restrict__ ebuf,
                          const float* __restrict__ den, const int* __restrict__ gstart,
                          const int* __restrict__ gend, float* __restrict__ pooled) {
    __shared__ float2 pl[512];
    int g = blockIdx.x, c = blockIdx.y;
    int tid = threadIdx.x;              // 512
    int fq = tid & 31, ng = tid >> 5;   // 32 feat-pairs x 16 node groups
    int s = gstart[g], e = gend[g];
    float2 acc = make_float2(0.f, 0.f);
    for (int n = s + ng; n < e; n += 16) {
        float wv = ebuf[n];
        union { unsigned u; half2v h2; } v;
        v.u = *(const unsigned*)(h + (size_t)n * 256 + c * 64 + fq * 2);
        acc.x += (float)v.h2[0] * wv;
        acc.y += (float)v.h2[1] * wv;
    }
    pl[tid] = acc;
    __syncthreads();
    if (tid < 32) {
        float2 a = pl[tid];
        #pragma unroll
        for (int q = 1; q < 16; ++q) {
            float2 t = pl[q * 32 + tid];
            a.x += t.x; a.y += t.y;
        }
        float d = (e > s) ? den[g] : 1.f;
        float inv = 1.f / d;
        pooled[g * 256 + c * 64 + fq * 2]     = (e > s) ? a.x * inv : 0.f;
        pooled[g * 256 + c * 64 + fq * 2 + 1] = (e > s) ? a.y * inv : 0.f;
    }
}

__global__ void cls_kernel(const float* __restrict__ pooled,
                           const float* __restrict__ cw1, const float* __restrict__ cb1,
                           const float* __restrict__ cw2, const float* __restrict__ cb2,
                           float* __restrict__ out) {
    __shared__ float pl[256];
    __shared__ float c2[256];
    int g = blockIdx.x;
    int tid = threadIdx.x;   // 128
    pl[tid] = pooled[g * 256 + tid];
    pl[tid + 128] = pooled[g * 256 + 128 + tid];
    __syncthreads();
    float a = cb1[tid];
    #pragma unroll 2
    for (int k = 0; k < H; ++k) a = fmaf(pl[k], cw1[(size_t)k * 128 + tid], a);
    a = fmaxf(a, 0.f);
    c2[tid * 2 + 0] = a * cw2[tid * 2 + 0];
    c2[tid * 2 + 1] = a * cw2[tid * 2 + 1];
    __syncthreads();
    if (tid < 2) {
        float sres = cb2[tid];
        for (int p = 0; p < 128; ++p) sres += c2[p * 2 + tid];
        out[g * 2 + tid] = sres;
    }
}

// ---------------- launch ----------------

extern "C" void kernel_launch(void* const* d_in, const int* in_sizes, int n_in,
                              void* d_out, int out_size, void* d_ws, size_t ws_size,
                              hipStream_t stream) {
    const float* x     = (const float*)d_in[0];
    const int*   ei    = (const int*)d_in[1];
    const int*   batch = (const int*)d_in[2];
    const float* w1_0  = (const float*)d_in[4];
    const float* b1_0  = (const float*)d_in[5];
    const float* w2_0  = (const float*)d_in[6];
    const float* b2_0  = (const float*)d_in[7];
    const float* lng0  = (const float*)d_in[8];
    const float* lnb0  = (const float*)d_in[9];
    const float* w1_1  = (const float*)d_in[10];
    const float* b1_1  = (const float*)d_in[11];
    const float* w2_1  = (const float*)d_in[12];
    const float* b2_1  = (const float*)d_in[13];
    const float* lng1  = (const float*)d_in[14];
    const float* lnb1  = (const float*)d_in[15];
    const float* gw1   = (const float*)d_in[16];
    const float* gb1   = (const float*)d_in[17];
    const float* gw2   = (const float*)d_in[18];
    const float* gb2   = (const float*)d_in[19];
    const float* cw1   = (const float*)d_in[20];
    const float* cb1   = (const float*)d_in[21];
    const float* cw2   = (const float*)d_in[22];
    const float* cb2   = (const float*)d_in[23];

    int N = in_sizes[2];
    int E = in_sizes[1] / 2;
    int G = out_size / 2;
    const int* src = ei;
    const int* dst = ei + E;

    // bucket shift: 512 nodes/bucket, NB <= 256
    int shift = 9;
    while ((((N - 1) >> shift) + 1) > 256) shift++;
    int NB = ((N - 1) >> shift) + 1;

    char* p = (char*)d_ws;
    auto alloc = [&](size_t bytes) {
        char* r = p;
        p += (bytes + 255) & ~(size_t)255;
        return r;
    };
    int*    row    = (int*)alloc((size_t)(N + 1) * 4);
    int*    srcl   = (int*)alloc((size_t)E * 4);
    u64*    pairs  = (u64*)alloc((size_t)E * 8);
    int*    bktCnt = (int*)alloc(256 * 4);
    int*    bktBase= (int*)alloc(257 * 4);
    int*    bktCur = (int*)alloc(256 * 4);
    float*  gate   = (float*)alloc((size_t)N * 4);
    float*  ebuf   = (float*)alloc((size_t)N * 4);
    float*  den    = (float*)alloc((size_t)G * 4);
    float*  pooled = (float*)alloc((size_t)G * 256 * 4);
    int*    gstart = (int*)alloc((size_t)G * 4);
    int*    gend   = (int*)alloc((size_t)G * 4);
    ushort* xb     = (ushort*)alloc((size_t)N * 128 * 2);
    ushort* hsum0  = (ushort*)alloc((size_t)N * 128 * 2);
    ushort* h1     = (ushort*)alloc((size_t)N * 256 * 2);
    ushort* hsum1  = (ushort*)alloc((size_t)N * 256 * 2);
    ushort* h2     = (ushort*)alloc((size_t)N * 256 * 2);
    ushort* w1t0   = (ushort*)alloc(128 * 256 * 2);
    ushort* w2t0   = (ushort*)alloc(256 * 256 * 2);
    ushort* w1t1   = (ushort*)alloc(256 * 256 * 2);
    ushort* w2t1   = (ushort*)alloc(256 * 256 * 2);
    ushort* gw1t   = (ushort*)alloc(128 * 256 * 2);

    // weight prep, x cast, bucketed CSR build
    prep_weights<<<1024, 256, 0, stream>>>(w1_0, w2_0, w1_1, w2_1, gw1,
                                           w1t0, w2t0, w1t1, w2t1, gw1t);
    xcast<<<(N * 32 + 255) / 256, 256, 0, stream>>>(x, (u64*)xb, N * 32);
    hipMemsetAsync(bktCnt, 0, 256 * 4, stream);
    bucket_hist<<<1024, 256, 0, stream>>>(dst, bktCnt, E, shift);
    scan_buckets<<<1, 256, 0, stream>>>(bktCnt, bktBase, bktCur, NB);
    bin_pass<<<(E + 4095) / 4096, 256, 0, stream>>>(src, dst, bktCur, pairs, E, shift);
    fill_bucket<<<NB, 256, 0, stream>>>(pairs, bktBase, row, srcl, N, shift, NB);

    int agg_blocks = (N + 3) / 4;
    int mlp_blocks = (N + 63) / 64;
    // layer 0
    aggregate0<<<agg_blocks, 256, 0, stream>>>((const unsigned*)xb, row, srcl,
                                               (unsigned*)hsum0, N);
    mlp_mfma<128, false><<<mlp_blocks, 256, 0, stream>>>(
        hsum0, w1t0, b1_0, w2t0, b2_0, lng0, lnb0, h1,
        nullptr, nullptr, nullptr, nullptr, nullptr, N);
    // layer 1 + fused gate
    aggregate1<<<agg_blocks, 256, 0, stream>>>((const u64*)h1, row, srcl,
                                               (u64*)hsum1, N);
    mlp_mfma<256, true><<<mlp_blocks, 256, 0, stream>>>(
        hsum1, w1t1, b1_1, w2t1, b2_1, lng1, lnb1, h2,
        gw1t, gb1, gw2, gb2, gate, N);
    // pooling + classifier
    hipMemsetAsync(gstart, 0, (size_t)G * 4, stream);
    hipMemsetAsync(gend, 0, (size_t)G * 4, stream);
    boundaries<<<(N + 255) / 256, 256, 0, stream>>>(batch, gstart, gend, N);
    gate_stats<<<G, 256, 0, stream>>>(gate, gstart, gend, ebuf, den);
    pool_feat<<<dim3(G, 4), 512, 0, stream>>>(h2, ebuf, den, gstart, gend, pooled);
    cls_kernel<<<G, 128, 0, stream>>>(pooled, cw1, cb1, cw2, cb2, (float*)d_out);
}

// Round 14
// 497.605 us; speedup vs baseline: 1.1839x; 1.0109x over previous
//
#include <hip/hip_runtime.h>
#include <math.h>

#define H 256

typedef float f32x4 __attribute__((ext_vector_type(4)));
typedef _Float16 half8 __attribute__((ext_vector_type(8)));
typedef _Float16 half4 __attribute__((ext_vector_type(4)));
typedef _Float16 half2v __attribute__((ext_vector_type(2)));
typedef unsigned long long u64;

__device__ inline unsigned pkh(float a, float b) {
    auto t = __builtin_amdgcn_cvt_pkrtz(a, b);
    union { decltype(t) h; unsigned u; } v; v.h = t; return v.u;
}
__device__ inline ushort f2h(float f) {
    union { _Float16 h; ushort u; } v; v.h = (_Float16)f; return v.u;
}
// async global->LDS copy, 16B per lane; lds dest must be wave-uniform base
__device__ inline void gload_lds16(const void* gp, void* lp) {
    __builtin_amdgcn_global_load_lds(
        (const __attribute__((address_space(1))) unsigned int*)gp,
        (__attribute__((address_space(3))) unsigned int*)lp,
        16, 0, 0);
}

// ---------------- bucketed CSR build ----------------
// bucket b = dst >> SHIFT (512 nodes/bucket, NB <= 256 buckets)

__global__ void bucket_hist(const int* __restrict__ dst, int* __restrict__ bktCnt,
                            int E, int shift) {
    __shared__ int h[256];
    int tid = threadIdx.x;
    h[tid] = 0;
    __syncthreads();
    for (int e = blockIdx.x * 256 + tid; e < E; e += gridDim.x * 256)
        atomicAdd(&h[dst[e] >> shift], 1);
    __syncthreads();
    if (h[tid]) atomicAdd(&bktCnt[tid], h[tid]);
}

// 1 block, 256 threads; nb <= 256
__global__ void scan_buckets(const int* __restrict__ cnt, int* __restrict__ base,
                             int* __restrict__ cur, int nb) {
    __shared__ int ws[4];
    int tid = threadIdx.x, lane = tid & 63, wid = tid >> 6;
    int v = (tid < nb) ? cnt[tid] : 0;
    int x = v;
    #pragma unroll
    for (int off = 1; off < 64; off <<= 1) {
        int t = __shfl_up(x, off, 64);
        if (lane >= off) x += t;
    }
    if (lane == 63) ws[wid] = x;
    __syncthreads();
    int wexc = 0;
    for (int w = 0; w < wid; ++w) wexc += ws[w];
    int excl = wexc + x - v;
    if (tid < nb) { base[tid] = excl; cur[tid] = excl; }
    if (tid == nb - 1) base[nb] = excl + v;   // = E
}

// bin edges into bucket-grouped pair buffer; 4096 edges/block
#define BIN_EPT 16
__global__ void __launch_bounds__(256) bin_pass(
        const int* __restrict__ src, const int* __restrict__ dst,
        int* __restrict__ bktCur, u64* __restrict__ pairs, int E, int shift) {
    __shared__ int hist[256];
    __shared__ int base_s[256];
    int tid = threadIdx.x;
    hist[tid] = 0;
    __syncthreads();
    int e0 = blockIdx.x * (256 * BIN_EPT);
    int mys[BIN_EPT], myd[BIN_EPT], myslot[BIN_EPT];
    #pragma unroll
    for (int i = 0; i < BIN_EPT; ++i) {
        int e = e0 + i * 256 + tid;
        if (e < E) {
            mys[i] = src[e];
            myd[i] = dst[e];
            myslot[i] = atomicAdd(&hist[myd[i] >> shift], 1);
        }
    }
    __syncthreads();
    base_s[tid] = hist[tid] ? atomicAdd(&bktCur[tid], hist[tid]) : 0;
    __syncthreads();
    #pragma unroll
    for (int i = 0; i < BIN_EPT; ++i) {
        int e = e0 + i * 256 + tid;
        if (e < E)
            pairs[base_s[myd[i] >> shift] + myslot[i]] =
                ((u64)(unsigned)myd[i] << 32) | (unsigned)mys[i];
    }
}

// one block per bucket: LDS degree count -> scan -> row + srcl fill
__global__ void __launch_bounds__(256) fill_bucket(
        const u64* __restrict__ pairs, const int* __restrict__ bktBase,
        int* __restrict__ row, int* __restrict__ srcl, int N, int shift, int NB) {
    __shared__ int deg[512];
    __shared__ int ws[4];
    int b = blockIdx.x;
    int n0 = b << shift;
    int nodes = (1 << shift); if (n0 + nodes > N) nodes = N - n0;
    int e0 = bktBase[b], e1 = bktBase[b + 1];
    int tid = threadIdx.x, lane = tid & 63, wid = tid >> 6;
    deg[tid] = 0; deg[tid + 256] = 0;
    __syncthreads();
    for (int e = e0 + tid; e < e1; e += 256) {
        int d = (int)(pairs[e] >> 32) - n0;
        atomicAdd(&deg[d], 1);
    }
    __syncthreads();
    // exclusive scan of 512 (2 elems/thread)
    int a0 = deg[2 * tid], a1 = deg[2 * tid + 1];
    int ps = a0 + a1;
    int x = ps;
    #pragma unroll
    for (int off = 1; off < 64; off <<= 1) {
        int t = __shfl_up(x, off, 64);
        if (lane >= off) x += t;
    }
    if (lane == 63) ws[wid] = x;
    __syncthreads();
    int wexc = 0;
    for (int w = 0; w < wid; ++w) wexc += ws[w];
    int p0 = wexc + x - ps;      // exclusive prefix of elem 2t
    int p1 = p0 + a0;
    if (2 * tid < nodes)     row[n0 + 2 * tid]     = e0 + p0;
    if (2 * tid + 1 < nodes) row[n0 + 2 * tid + 1] = e0 + p1;
    if (b == NB - 1 && tid == 0) row[N] = e1;
    __syncthreads();
    deg[2 * tid] = e0 + p0;
    deg[2 * tid + 1] = e0 + p1;
    __syncthreads();
    for (int e = e0 + tid; e < e1; e += 256) {
        u64 pr = pairs[e];
        int d = (int)(pr >> 32) - n0;
        int p = atomicAdd(&deg[d], 1);
        srcl[p] = (int)(pr & 0xffffffffu);
    }
}

// ---------------- weight prep: fp32 -> fp16 transposed ----------------

__global__ void prep_weights(const float* __restrict__ w10, const float* __restrict__ w20,
                             const float* __restrict__ w11, const float* __restrict__ w21,
                             const float* __restrict__ gw1,
                             ushort* __restrict__ w1t0, ushort* __restrict__ w2t0,
                             ushort* __restrict__ w1t1, ushort* __restrict__ w2t1,
                             ushort* __restrict__ gw1t) {
    int i = blockIdx.x * 256 + threadIdx.x;
    if (i < 32768) {                       // w10: 128x256
        int k = i >> 8, n = i & 255;
        w1t0[n * 128 + k] = f2h(w10[i]);
    } else if (i < 32768 + 65536) {        // w20: 256x256
        int j = i - 32768; int k = j >> 8, n = j & 255;
        w2t0[n * 256 + k] = f2h(w20[j]);
    } else if (i < 32768 + 131072) {       // w11: 256x256
        int j = i - (32768 + 65536); int k = j >> 8, n = j & 255;
        w1t1[n * 256 + k] = f2h(w11[j]);
    } else if (i < 32768 + 196608) {       // w21: 256x256
        int j = i - (32768 + 131072); int k = j >> 8, n = j & 255;
        w2t1[n * 256 + k] = f2h(w21[j]);
    } else if (i < 32768 + 196608 + 32768) { // gw1: 256x128
        int j = i - (32768 + 196608); int k = j >> 7, n = j & 127;
        gw1t[n * 256 + k] = f2h(gw1[j]);
    }
}

// ---------------- x -> fp16 ----------------

__global__ void xcast(const float* __restrict__ x, u64* __restrict__ xb, int n4) {
    int i = blockIdx.x * 256 + threadIdx.x;
    if (i < n4) {
        f32x4 v = ((const f32x4*)x)[i];
        xb[i] = (u64)pkh(v[0], v[1]) | ((u64)pkh(v[2], v[3]) << 32);
    }
}

// ---------------- aggregation (wave per node, 16-deep unroll) ----------------
// Output rows are written with the 16B-granule XOR swizzle (g ^= n&7) so the
// MLP kernel's linear global_load_lds staging lands conflict-free in LDS.

__global__ void aggregate0(const unsigned* __restrict__ xb, const int* __restrict__ row,
                           const int* __restrict__ srcl, unsigned* __restrict__ out, int N) {
    int n = blockIdx.x * 4 + (threadIdx.x >> 6);
    int f = threadIdx.x & 63;
    if (n >= N) return;
    union U { unsigned u; half2v h; };
    int s0 = row[n], s1 = row[n + 1];
    U a[16];
    a[0].u = xb[(size_t)n * 64 + f];
    #pragma unroll
    for (int q = 1; q < 16; ++q) a[q].h = (half2v)0;
    for (int base = s0; base < s1; base += 64) {
        int cnt = s1 - base; if (cnt > 64) cnt = 64;
        int idx = srcl[base + (f < cnt ? f : 0)];
        int j = 0;
        for (; j + 15 < cnt; j += 16) {
            U u[16];
            #pragma unroll
            for (int q = 0; q < 16; ++q)
                u[q].u = xb[(size_t)__builtin_amdgcn_readlane(idx, j + q) * 64 + f];
            #pragma unroll
            for (int q = 0; q < 16; ++q) a[q].h += u[q].h;
        }
        for (; j + 3 < cnt; j += 4) {
            U u[4];
            #pragma unroll
            for (int q = 0; q < 4; ++q)
                u[q].u = xb[(size_t)__builtin_amdgcn_readlane(idx, j + q) * 64 + f];
            #pragma unroll
            for (int q = 0; q < 4; ++q) a[q].h += u[q].h;
        }
        for (; j < cnt; ++j) {
            U u0; u0.u = xb[(size_t)__builtin_amdgcn_readlane(idx, j) * 64 + f];
            a[0].h += u0.h;
        }
    }
    #pragma unroll
    for (int q = 0; q < 8; ++q) a[q].h += a[q + 8].h;
    #pragma unroll
    for (int q = 0; q < 4; ++q) a[q].h += a[q + 4].h;
    a[0].h += a[2].h; a[1].h += a[3].h;
    a[0].h += a[1].h;
    int of = (((f >> 2) ^ (n & 7)) << 2) | (f & 3);   // 16B-granule swizzle
    out[(size_t)n * 64 + of] = a[0].u;
}

__global__ void aggregate1(const u64* __restrict__ h, const int* __restrict__ row,
                           const int* __restrict__ srcl, u64* __restrict__ out, int N) {
    int n = blockIdx.x * 4 + (threadIdx.x >> 6);
    int f = threadIdx.x & 63;
    if (n >= N) return;
    union U { u64 u; half4 h; };
    int s0 = row[n], s1 = row[n + 1];
    U a[16];
    a[0].u = h[(size_t)n * 64 + f];
    #pragma unroll
    for (int q = 1; q < 16; ++q) a[q].h = (half4)0;
    for (int base = s0; base < s1; base += 64) {
        int cnt = s1 - base; if (cnt > 64) cnt = 64;
        int idx = srcl[base + (f < cnt ? f : 0)];
        int j = 0;
        for (; j + 15 < cnt; j += 16) {
            U u[16];
            #pragma unroll
            for (int q = 0; q < 16; ++q)
                u[q].u = h[(size_t)__builtin_amdgcn_readlane(idx, j + q) * 64 + f];
            #pragma unroll
            for (int q = 0; q < 16; ++q) a[q].h += u[q].h;
        }
        for (; j + 3 < cnt; j += 4) {
            U u[4];
            #pragma unroll
            for (int q = 0; q < 4; ++q)
                u[q].u = h[(size_t)__builtin_amdgcn_readlane(idx, j + q) * 64 + f];
            #pragma unroll
            for (int q = 0; q < 4; ++q) a[q].h += u[q].h;
        }
        for (; j < cnt; ++j) {
            U u0; u0.u = h[(size_t)__builtin_amdgcn_readlane(idx, j) * 64 + f];
            a[0].h += u0.h;
        }
    }
    #pragma unroll
    for (int q = 0; q < 8; ++q) a[q].h += a[q + 8].h;
    #pragma unroll
    for (int q = 0; q < 4; ++q) a[q].h += a[q + 4].h;
    a[0].h += a[2].h; a[1].h += a[3].h;
    a[0].h += a[1].h;
    int of = (((f >> 1) ^ (n & 7)) << 1) | (f & 1);   // 16B-granule swizzle
    out[(size_t)n * 64 + of] = a[0].u;
}

// ---------------- fused MFMA MLP + LN (+ gate), 8 waves ----------------
// 8 waves x 64 nodes/block; ft-split: wave w owns ft-tiles {2w, 2w+1}
// (GEMM1/GEMM2) resp tile {w} (gate). Same 64-node tile & LDS as the 4-wave
// version but 2x waves/SIMD for latency hiding (acc halves to 2x4 f32x4).
// Swapped MFMA: C col = node (lane&15), C row = feat (4*(lane>>4)+r).

template<int K1, bool DO_GATE>
__global__ void __launch_bounds__(512, 4) mlp_mfma(
        const ushort* __restrict__ hsum, const ushort* __restrict__ w1t,
        const float* __restrict__ b1, const ushort* __restrict__ w2t,
        const float* __restrict__ b2, const float* __restrict__ lng,
        const float* __restrict__ lnb, ushort* __restrict__ hout,
        const ushort* __restrict__ gw1t, const float* __restrict__ gb1,
        const float* __restrict__ gw2, const float* __restrict__ gb2,
        float* __restrict__ gate, int N) {
    constexpr int ROWB = K1 * 2;           // bytes per input row
    constexpr int TILEB = 64 * ROWB;       // staged A-tile bytes
    __shared__ ushort hsum_t[64 * K1];     // swizzled input tile (staged)
    __shared__ ushort hid[64 * 256];       // 32KB, swizzled [node][feat]
    __shared__ float2 lnred[8 * 64];       // [wave][node]
    __shared__ float gred[8 * 64];
    int tid = threadIdx.x;
    int w = tid >> 6, lane = tid & 63;
    int ll = lane & 15, kg = lane >> 4;
    int n0 = blockIdx.x * 64;

    // ---- async stage A-tile: 8KB per round (512 lanes x 16B) ----
    {
        const char* gs = (const char*)hsum;
        #pragma unroll
        for (int r = 0; r < TILEB / 8192; ++r) {
            int off = r * 8192 + w * 1024;        // wave-uniform LDS base
            int myoff = off + lane * 16;
            int mynode = myoff / ROWB;
            int inrow = myoff - mynode * ROWB;
            int gn = n0 + mynode; if (gn >= N) gn = N - 1;
            gload_lds16(gs + (size_t)gn * ROWB + inrow, (char*)hsum_t + off);
        }
    }
    __syncthreads();   // drains vmcnt before barrier

    // ---- GEMM1: B-frags from LDS, weights 1-ahead from L2 ----
    constexpr int KC1 = K1 / 32;
    f32x4 acc[2][4];
    #pragma unroll
    for (int f = 0; f < 2; ++f)
        #pragma unroll
        for (int nt = 0; nt < 4; ++nt) acc[f][nt] = (f32x4){0.f, 0.f, 0.f, 0.f};
    {
        half8 wcur[2];
        #pragma unroll
        for (int f = 0; f < 2; ++f)
            wcur[f] = *(const half8*)(w1t + (size_t)(16 * (2 * w + f) + ll) * K1 + kg * 8);
        #pragma unroll
        for (int kc = 0; kc < KC1; ++kc) {
            half8 wnx[2];
            if (kc + 1 < KC1) {
                #pragma unroll
                for (int f = 0; f < 2; ++f)
                    wnx[f] = *(const half8*)(w1t + (size_t)(16 * (2 * w + f) + ll) * K1 + (kc + 1) * 32 + kg * 8);
            }
            half8 bfr[4];
            #pragma unroll
            for (int nt = 0; nt < 4; ++nt) {
                int node = 16 * nt + ll;
                bfr[nt] = *(const half8*)((char*)hsum_t + node * ROWB +
                                          (((kc * 4 + kg) ^ (node & 7)) << 4));
            }
            #pragma unroll
            for (int f = 0; f < 2; ++f)
                #pragma unroll
                for (int nt = 0; nt < 4; ++nt)
                    acc[f][nt] = __builtin_amdgcn_mfma_f32_16x16x32_f16(wcur[f], bfr[nt], acc[f][nt], 0, 0, 0);
            if (kc + 1 < KC1) {
                #pragma unroll
                for (int f = 0; f < 2; ++f) wcur[f] = wnx[f];
            }
        }
    }
    // bias + relu + pack -> swizzled LDS
    #pragma unroll
    for (int f = 0; f < 2; ++f) {
        int feat0 = 16 * (2 * w + f) + 4 * kg;
        f32x4 bq = *(const f32x4*)(b1 + feat0);
        int fb = feat0 * 2;
        #pragma unroll
        for (int nt = 0; nt < 4; ++nt) {
            int node = 16 * nt + ll;
            float v0 = fmaxf(acc[f][nt][0] + bq[0], 0.f);
            float v1 = fmaxf(acc[f][nt][1] + bq[1], 0.f);
            float v2 = fmaxf(acc[f][nt][2] + bq[2], 0.f);
            float v3 = fmaxf(acc[f][nt][3] + bq[3], 0.f);
            unsigned lo = pkh(v0, v1), hi2 = pkh(v2, v3);
            int sb = node * 512 + ((((fb >> 4) ^ (node & 7))) << 4) + (fb & 15);
            *(u64*)((char*)hid + sb) = (u64)lo | ((u64)hi2 << 32);
        }
    }
    __syncthreads();

    // ---- GEMM2 with 1-ahead weight prefetch (LDS reads stay inline) ----
    #pragma unroll
    for (int f = 0; f < 2; ++f)
        #pragma unroll
        for (int nt = 0; nt < 4; ++nt) acc[f][nt] = (f32x4){0.f, 0.f, 0.f, 0.f};
    {
        half8 wcur[2];
        #pragma unroll
        for (int f = 0; f < 2; ++f)
            wcur[f] = *(const half8*)(w2t + (size_t)(16 * (2 * w + f) + ll) * 256 + kg * 8);
        #pragma unroll
        for (int kc = 0; kc < 8; ++kc) {
            half8 wnx[2];
            if (kc < 7) {
                #pragma unroll
                for (int f = 0; f < 2; ++f)
                    wnx[f] = *(const half8*)(w2t + (size_t)(16 * (2 * w + f) + ll) * 256 + (kc + 1) * 32 + kg * 8);
            }
            half8 bfr[4];
            int fb = kc * 64 + kg * 16;
            #pragma unroll
            for (int nt = 0; nt < 4; ++nt) {
                int node = 16 * nt + ll;
                int sb = node * 512 + ((((fb >> 4) ^ (node & 7))) << 4);
                bfr[nt] = *(const half8*)((char*)hid + sb);
            }
            #pragma unroll
            for (int f = 0; f < 2; ++f)
                #pragma unroll
                for (int nt = 0; nt < 4; ++nt)
                    acc[f][nt] = __builtin_amdgcn_mfma_f32_16x16x32_f16(wcur[f], bfr[nt], acc[f][nt], 0, 0, 0);
            if (kc < 7) {
                #pragma unroll
                for (int f = 0; f < 2; ++f) wcur[f] = wnx[f];
            }
        }
    }

    // ---- LayerNorm: per-node partials over this wave's 32 feats ----
    float sA[4] = {0, 0, 0, 0}, sB[4] = {0, 0, 0, 0};
    #pragma unroll
    for (int f = 0; f < 2; ++f) {
        int feat0 = 16 * (2 * w + f) + 4 * kg;
        f32x4 bq = *(const f32x4*)(b2 + feat0);
        #pragma unroll
        for (int nt = 0; nt < 4; ++nt) {
            #pragma unroll
            for (int r = 0; r < 4; ++r) {
                float v = acc[f][nt][r] + bq[r];
                acc[f][nt][r] = v;
                sA[nt] += v; sB[nt] += v * v;
            }
        }
    }
    #pragma unroll
    for (int nt = 0; nt < 4; ++nt) {
        sA[nt] += __shfl_xor(sA[nt], 16, 64); sA[nt] += __shfl_xor(sA[nt], 32, 64);
        sB[nt] += __shfl_xor(sB[nt], 16, 64); sB[nt] += __shfl_xor(sB[nt], 32, 64);
    }
    if (lane < 16) {
        #pragma unroll
        for (int nt = 0; nt < 4; ++nt)
            lnred[w * 64 + nt * 16 + ll] = make_float2(sA[nt], sB[nt]);
    }
    __syncthreads();

    float mu[4], rs[4];
    #pragma unroll
    for (int nt = 0; nt < 4; ++nt) {
        float a = 0.f, b = 0.f;
        #pragma unroll
        for (int wv = 0; wv < 8; ++wv) {
            float2 t = lnred[wv * 64 + nt * 16 + ll];
            a += t.x; b += t.y;
        }
        float m = a * (1.f / 256.f);
        mu[nt] = m;
        rs[nt] = rsqrtf(b * (1.f / 256.f) - m * m + 1e-5f);
    }

    // ---- LN apply + relu: write h global (+ hid2 to LDS for gate) ----
    #pragma unroll
    for (int f = 0; f < 2; ++f) {
        int feat0 = 16 * (2 * w + f) + 4 * kg;
        f32x4 gq = *(const f32x4*)(lng + feat0);
        f32x4 bq = *(const f32x4*)(lnb + feat0);
        int fb = feat0 * 2;
        #pragma unroll
        for (int nt = 0; nt < 4; ++nt) {
            int node = 16 * nt + ll;
            int n = n0 + node;
            float v0 = fmaxf((acc[f][nt][0] - mu[nt]) * rs[nt] * gq[0] + bq[0], 0.f);
            float v1 = fmaxf((acc[f][nt][1] - mu[nt]) * rs[nt] * gq[1] + bq[1], 0.f);
            float v2 = fmaxf((acc[f][nt][2] - mu[nt]) * rs[nt] * gq[2] + bq[2], 0.f);
            float v3 = fmaxf((acc[f][nt][3] - mu[nt]) * rs[nt] * gq[3] + bq[3], 0.f);
            unsigned lo = pkh(v0, v1), hi2 = pkh(v2, v3);
            u64 pv = (u64)lo | ((u64)hi2 << 32);
            if (n < N)
                *(u64*)(hout + (size_t)n * 256 + feat0) = pv;
            if (DO_GATE) {
                int sb = node * 512 + ((((fb >> 4) ^ (node & 7))) << 4) + (fb & 15);
                *(u64*)((char*)hid + sb) = pv;
            }
        }
    }

    // ---- gate MLP (ft-split: wave w owns gate-ft tile {w}) ----
    if (DO_GATE) {
        __syncthreads();
        f32x4 ga[4];
        #pragma unroll
        for (int nt = 0; nt < 4; ++nt) ga[nt] = (f32x4){0.f, 0.f, 0.f, 0.f};
        half8 wcur = *(const half8*)(gw1t + (size_t)(16 * w + ll) * 256 + kg * 8);
        #pragma unroll
        for (int kc = 0; kc < 8; ++kc) {
            half8 wnx;
            if (kc < 7)
                wnx = *(const half8*)(gw1t + (size_t)(16 * w + ll) * 256 + (kc + 1) * 32 + kg * 8);
            half8 bfr[4];
            int fb = kc * 64 + kg * 16;
            #pragma unroll
            for (int nt = 0; nt < 4; ++nt) {
                int node = 16 * nt + ll;
                int sb = node * 512 + ((((fb >> 4) ^ (node & 7))) << 4);
                bfr[nt] = *(const half8*)((char*)hid + sb);
            }
            #pragma unroll
            for (int nt = 0; nt < 4; ++nt)
                ga[nt] = __builtin_amdgcn_mfma_f32_16x16x32_f16(wcur, bfr[nt], ga[nt], 0, 0, 0);
            if (kc < 7) wcur = wnx;
        }
        float gp[4] = {0, 0, 0, 0};
        {
            int feat0 = 16 * w + 4 * kg;
            f32x4 gbq = *(const f32x4*)(gb1 + feat0);
            f32x4 gwq = *(const f32x4*)(gw2 + feat0);
            #pragma unroll
            for (int nt = 0; nt < 4; ++nt)
                #pragma unroll
                for (int r = 0; r < 4; ++r)
                    gp[nt] += fmaxf(ga[nt][r] + gbq[r], 0.f) * gwq[r];
        }
        #pragma unroll
        for (int nt = 0; nt < 4; ++nt) {
            gp[nt] += __shfl_xor(gp[nt], 16, 64);
            gp[nt] += __shfl_xor(gp[nt], 32, 64);
        }
        if (lane < 16) {
            #pragma unroll
            for (int nt = 0; nt < 4; ++nt)
                gred[w * 64 + nt * 16 + ll] = gp[nt];
        }
        __syncthreads();
        if (w == 0 && lane < 16) {
            #pragma unroll
            for (int nt = 0; nt < 4; ++nt) {
                int n = n0 + 16 * nt + ll;
                if (n < N) {
                    float gs = 0.f;
                    #pragma unroll
                    for (int wv = 0; wv < 8; ++wv)
                        gs += gred[wv * 64 + nt * 16 + ll];
                    gate[n] = gs + gb2[0];
                }
            }
        }
    }
}

// ---------------- graph ranges ----------------

__global__ void boundaries(const int* __restrict__ batch, int* __restrict__ gstart,
                           int* __restrict__ gend, int N) {
    int i = blockIdx.x * blockDim.x + threadIdx.x;
    if (i >= N) return;
    int b = batch[i];
    if (i == 0 || batch[i - 1] != b) gstart[b] = i;
    if (i == N - 1 || batch[i + 1] != b) gend[b] = i + 1;
}

// ---------------- softmax pooling, split ----------------

__global__ void gate_stats(const float* __restrict__ gate, const int* __restrict__ gstart,
                           const int* __restrict__ gend, float* __restrict__ ebuf,
                           float* __restrict__ den) {
    __shared__ float red[256];
    int g = blockIdx.x;
    int tid = threadIdx.x;   // 256
    int s = gstart[g], e = gend[g];
    float lmax = -INFINITY;
    for (int n = s + tid; n < e; n += 256) lmax = fmaxf(lmax, gate[n]);
    red[tid] = lmax;
    __syncthreads();
    for (int off = 128; off > 0; off >>= 1) {
        if (tid < off) red[tid] = fmaxf(red[tid], red[tid + off]);
        __syncthreads();
    }
    float gmax = red[0];
    __syncthreads();
    float lsum = 0.f;
    for (int n = s + tid; n < e; n += 256) {
        float ev = expf(gate[n] - gmax);
        ebuf[n] = ev;
        lsum += ev;
    }
    red[tid] = lsum;
    __syncthreads();
    for (int off = 128; off > 0; off >>= 1) {
        if (tid < off) red[tid] += red[tid + off];
        __syncthreads();
    }
    if (tid == 0) den[g] = red[0];
}

// grid (G, 4), 512 threads: block handles 64 feats of one graph, 16 node groups
__global__ void pool_feat(const ushort* __restrict__ h, const float* __restrict__ ebuf,
                          const float* __restrict__ den, const int* __restrict__ gstart,
                          const int* __restrict__ gend, float* __restrict__ pooled) {
    __shared__ float2 pl[512];
    int g = blockIdx.x, c = blockIdx.y;
    int tid = threadIdx.x;              // 512
    int fq = tid & 31, ng = tid >> 5;   // 32 feat-pairs x 16 node groups
    int s = gstart[g], e = gend[g];
    float2 acc = make_float2(0.f, 0.f);
    for (int n = s + ng; n < e; n += 16) {
        float wv = ebuf[n];
        union { unsigned u; half2v h2; } v;
        v.u = *(const unsigned*)(h + (size_t)n * 256 + c * 64 + fq * 2);
        acc.x += (float)v.h2[0] * wv;
        acc.y += (float)v.h2[1] * wv;
    }
    pl[tid] = acc;
    __syncthreads();
    if (tid < 32) {
        float2 a = pl[tid];
        #pragma unroll
        for (int q = 1; q < 16; ++q) {
            float2 t = pl[q * 32 + tid];
            a.x += t.x; a.y += t.y;
        }
        float d = (e > s) ? den[g] : 1.f;
        float inv = 1.f / d;
        pooled[g * 256 + c * 64 + fq * 2]     = (e > s) ? a.x * inv : 0.f;
        pooled[g * 256 + c * 64 + fq * 2 + 1] = (e > s) ? a.y * inv : 0.f;
    }
}

__global__ void cls_kernel(const float* __restrict__ pooled,
                           const float* __restrict__ cw1, const float* __restrict__ cb1,
                           const float* __restrict__ cw2, const float* __restrict__ cb2,
                           float* __restrict__ out) {
    __shared__ float pl[256];
    __shared__ float c2[256];
    int g = blockIdx.x;
    int tid = threadIdx.x;   // 128
    pl[tid] = pooled[g * 256 + tid];
    pl[tid + 128] = pooled[g * 256 + 128 + tid];
    __syncthreads();
    float a = cb1[tid];
    #pragma unroll 2
    for (int k = 0; k < H; ++k) a = fmaf(pl[k], cw1[(size_t)k * 128 + tid], a);
    a = fmaxf(a, 0.f);
    c2[tid * 2 + 0] = a * cw2[tid * 2 + 0];
    c2[tid * 2 + 1] = a * cw2[tid * 2 + 1];
    __syncthreads();
    if (tid < 2) {
        float sres = cb2[tid];
        for (int p = 0; p < 128; ++p) sres += c2[p * 2 + tid];
        out[g * 2 + tid] = sres;
    }
}

// ---------------- launch ----------------

extern "C" void kernel_launch(void* const* d_in, const int* in_sizes, int n_in,
                              void* d_out, int out_size, void* d_ws, size_t ws_size,
                              hipStream_t stream) {
    const float* x     = (const float*)d_in[0];
    const int*   ei    = (const int*)d_in[1];
    const int*   batch = (const int*)d_in[2];
    const float* w1_0  = (const float*)d_in[4];
    const float* b1_0  = (const float*)d_in[5];
    const float* w2_0  = (const float*)d_in[6];
    const float* b2_0  = (const float*)d_in[7];
    const float* lng0  = (const float*)d_in[8];
    const float* lnb0  = (const float*)d_in[9];
    const float* w1_1  = (const float*)d_in[10];
    const float* b1_1  = (const float*)d_in[11];
    const float* w2_1  = (const float*)d_in[12];
    const float* b2_1  = (const float*)d_in[13];
    const float* lng1  = (const float*)d_in[14];
    const float* lnb1  = (const float*)d_in[15];
    const float* gw1   = (const float*)d_in[16];
    const float* gb1   = (const float*)d_in[17];
    const float* gw2   = (const float*)d_in[18];
    const float* gb2   = (const float*)d_in[19];
    const float* cw1   = (const float*)d_in[20];
    const float* cb1   = (const float*)d_in[21];
    const float* cw2   = (const float*)d_in[22];
    const float* cb2   = (const float*)d_in[23];

    int N = in_sizes[2];
    int E = in_sizes[1] / 2;
    int G = out_size / 2;
    const int* src = ei;
    const int* dst = ei + E;

    // bucket shift: 512 nodes/bucket, NB <= 256
    int shift = 9;
    while ((((N - 1) >> shift) + 1) > 256) shift++;
    int NB = ((N - 1) >> shift) + 1;

    char* p = (char*)d_ws;
    auto alloc = [&](size_t bytes) {
        char* r = p;
        p += (bytes + 255) & ~(size_t)255;
        return r;
    };
    int*    row    = (int*)alloc((size_t)(N + 1) * 4);
    int*    srcl   = (int*)alloc((size_t)E * 4);
    u64*    pairs  = (u64*)alloc((size_t)E * 8);
    int*    bktCnt = (int*)alloc(256 * 4);
    int*    bktBase= (int*)alloc(257 * 4);
    int*    bktCur = (int*)alloc(256 * 4);
    float*  gate   = (float*)alloc((size_t)N * 4);
    float*  ebuf   = (float*)alloc((size_t)N * 4);
    float*  den    = (float*)alloc((size_t)G * 4);
    float*  pooled = (float*)alloc((size_t)G * 256 * 4);
    int*    gstart = (int*)alloc((size_t)G * 4);
    int*    gend   = (int*)alloc((size_t)G * 4);
    ushort* xb     = (ushort*)alloc((size_t)N * 128 * 2);
    ushort* hsum0  = (ushort*)alloc((size_t)N * 128 * 2);
    ushort* h1     = (ushort*)alloc((size_t)N * 256 * 2);
    ushort* hsum1  = (ushort*)alloc((size_t)N * 256 * 2);
    ushort* h2     = (ushort*)alloc((size_t)N * 256 * 2);
    ushort* w1t0   = (ushort*)alloc(128 * 256 * 2);
    ushort* w2t0   = (ushort*)alloc(256 * 256 * 2);
    ushort* w1t1   = (ushort*)alloc(256 * 256 * 2);
    ushort* w2t1   = (ushort*)alloc(256 * 256 * 2);
    ushort* gw1t   = (ushort*)alloc(128 * 256 * 2);

    // weight prep, x cast, bucketed CSR build
    prep_weights<<<1024, 256, 0, stream>>>(w1_0, w2_0, w1_1, w2_1, gw1,
                                           w1t0, w2t0, w1t1, w2t1, gw1t);
    xcast<<<(N * 32 + 255) / 256, 256, 0, stream>>>(x, (u64*)xb, N * 32);
    hipMemsetAsync(bktCnt, 0, 256 * 4, stream);
    bucket_hist<<<1024, 256, 0, stream>>>(dst, bktCnt, E, shift);
    scan_buckets<<<1, 256, 0, stream>>>(bktCnt, bktBase, bktCur, NB);
    bin_pass<<<(E + 4095) / 4096, 256, 0, stream>>>(src, dst, bktCur, pairs, E, shift);
    fill_bucket<<<NB, 256, 0, stream>>>(pairs, bktBase, row, srcl, N, shift, NB);

    int agg_blocks = (N + 3) / 4;
    int mlp_blocks = (N + 63) / 64;
    // layer 0
    aggregate0<<<agg_blocks, 256, 0, stream>>>((const unsigned*)xb, row, srcl,
                                               (unsigned*)hsum0, N);
    mlp_mfma<128, false><<<mlp_blocks, 512, 0, stream>>>(
        hsum0, w1t0, b1_0, w2t0, b2_0, lng0, lnb0, h1,
        nullptr, nullptr, nullptr, nullptr, nullptr, N);
    // layer 1 + fused gate
    aggregate1<<<agg_blocks, 256, 0, stream>>>((const u64*)h1, row, srcl,
                                               (u64*)hsum1, N);
    mlp_mfma<256, true><<<mlp_blocks, 512, 0, stream>>>(
        hsum1, w1t1, b1_1, w2t1, b2_1, lng1, lnb1, h2,
        gw1t, gb1, gw2, gb2, gate, N);
    // pooling + classifier
    hipMemsetAsync(gstart, 0, (size_t)G * 4, stream);
    hipMemsetAsync(gend, 0, (size_t)G * 4, stream);
    boundaries<<<(N + 255) / 256, 256, 0, stream>>>(batch, gstart, gend, N);
    gate_stats<<<G, 256, 0, stream>>>(gate, gstart, gend, ebuf, den);
    pool_feat<<<dim3(G, 4), 512, 0, stream>>>(h2, ebuf, den, gstart, gend, pooled);
    cls_kernel<<<G, 128, 0, stream>>>(pooled, cw1, cb1, cw2, cb2, (float*)d_out);
}